// Round 10
// baseline (334.705 us; speedup 1.0000x reference)
//
#include <hip/hip_runtime.h>
#include <hip/hip_bf16.h>
#include <stdint.h>

#define NN 50000
#define NE 600000
#define NP 200000
#define SCAN_CHUNK 1024
#define NB_SCAN ((NN + SCAN_CHUNK - 1) / SCAN_CHUNK)   // 49

// prep_all block ranges
#define PB_W    400                          // weight prep: 102400 threads
#define PB_CNT  ((NE + 255) / 256)           // 2344
#define PB_PF   ((NP * 32 / 8 + 255) / 256)  // 3125

typedef __attribute__((ext_vector_type(8))) short short8;
typedef __attribute__((ext_vector_type(4))) float f32x4;

static __device__ __forceinline__ unsigned short f2bf(float f) {
  union { float f; unsigned u; } a; a.f = f;
  unsigned r = a.u + 0x7fff + ((a.u >> 16) & 1);
  return (unsigned short)(r >> 16);
}
static __device__ __forceinline__ float bf2f(unsigned short h) {
  union { unsigned u; float f; } a; a.u = ((unsigned)h) << 16;
  return a.f;
}
static __device__ __forceinline__ float lo16f(unsigned w) {
  union { unsigned u; float f; } a; a.u = w << 16; return a.f;
}
static __device__ __forceinline__ float hi16f(unsigned w) {
  union { unsigned u; float f; } a; a.u = w & 0xffff0000u; return a.f;
}

// ---------------- fused prep: weight transpose/split + degree count + pf cast ----------------

__global__ __launch_bounds__(256) void prep_all(
    const float* __restrict__ embW, const float* __restrict__ convW,
    const float* __restrict__ W1, const float* __restrict__ W2,
    const int* __restrict__ erow, const float* __restrict__ pf,
    unsigned short* __restrict__ embT_hi, unsigned short* __restrict__ embT_lo,
    unsigned short* __restrict__ convT_hi, unsigned short* __restrict__ convT_lo,
    unsigned short* __restrict__ W1T, unsigned short* __restrict__ W2T,
    int* __restrict__ counts, unsigned short* __restrict__ pf_bf) {
  const int b = blockIdx.x, t = threadIdx.x;
  if (b < PB_W) {
    int idx = b * 256 + t;
    if (idx < 8192) {
      int n = idx >> 6, k = idx & 63;
      float v = embW[(size_t)k * 128 + n];
      unsigned short h = f2bf(v);
      embT_hi[idx] = h;
      embT_lo[idx] = f2bf(v - bf2f(h));
    } else if (idx < 8192 + 49152) {
      int i2 = idx - 8192;
      int l = i2 >> 14, n = (i2 >> 7) & 127, k = i2 & 127;
      float v = convW[(size_t)l * 16384 + (size_t)k * 128 + n];
      unsigned short h = f2bf(v);
      convT_hi[i2] = h;
      convT_lo[i2] = f2bf(v - bf2f(h));
    } else if (idx < 8192 + 49152 + 36864) {
      int i3 = idx - 57344;
      int n = i3 / 288, k = i3 % 288;
      W1T[i3] = f2bf(W1[(size_t)k * 128 + n]);
    } else if (idx < 8192 + 49152 + 36864 + 8192) {
      int i4 = idx - 94208;
      int n = i4 >> 7, k = i4 & 127;
      W2T[i4] = f2bf(W2[(size_t)k * 64 + n]);
    }
  } else if (b < PB_W + PB_CNT) {
    int e = (b - PB_W) * 256 + t;
    if (e < NE) atomicAdd(&counts[erow[e]], 1);
  } else {
    int i = (b - PB_W - PB_CNT) * 256 + t;   // group of 8 elements
    if (i < NP * 32 / 8) {
      const float4* s = (const float4*)(pf + (size_t)i * 8);
      float4 v0 = s[0], v1 = s[1];
      short8 o;
      o[0] = (short)f2bf(v0.x); o[1] = (short)f2bf(v0.y);
      o[2] = (short)f2bf(v0.z); o[3] = (short)f2bf(v0.w);
      o[4] = (short)f2bf(v1.x); o[5] = (short)f2bf(v1.y);
      o[6] = (short)f2bf(v1.z); o[7] = (short)f2bf(v1.w);
      *(short8*)(pf_bf + (size_t)i * 8) = o;
    }
  }
}

// ---------------- graph build ----------------

__global__ __launch_bounds__(256) void scan_partial_dis(const int* __restrict__ counts,
                                                        int* __restrict__ bsum,
                                                        float* __restrict__ dis) {
  const int b = blockIdx.x, t = threadIdx.x;
  const int base = b * SCAN_CHUNK;
  int s = 0;
  for (int j = t; j < SCAN_CHUNK; j += 256) {
    int i = base + j;
    if (i < NN) {
      int cv = counts[i];
      s += cv;
      dis[i] = rsqrtf((float)cv + 1.0f);
    }
  }
  __shared__ int red[4];
#pragma unroll
  for (int off = 32; off; off >>= 1) s += __shfl_down(s, off);
  if ((t & 63) == 0) red[t >> 6] = s;
  __syncthreads();
  if (t == 0) bsum[b] = red[0] + red[1] + red[2] + red[3];
}

__global__ __launch_bounds__(256) void scan_final(const int* __restrict__ counts,
                                                  const int* __restrict__ bsum,
                                                  int* __restrict__ row_ptr,
                                                  int* __restrict__ cursor) {
  const int b = blockIdx.x, t = threadIdx.x;
  __shared__ int sb[64];
  if (t < 64) {                       // wave 0: exclusive prefix of bsum[49]
    int v = (t < NB_SCAN) ? bsum[t] : 0;
    int orig = v;
#pragma unroll
    for (int off = 1; off < 64; off <<= 1) {
      int u = __shfl_up(v, off);
      if (t >= off) v += u;
    }
    sb[t] = v - orig;
  }
  const int i0 = b * SCAN_CHUNK + t * 4;
  int c[4]; int s = 0;
#pragma unroll
  for (int r = 0; r < 4; ++r) { int i = i0 + r; c[r] = (i < NN) ? counts[i] : 0; s += c[r]; }
  __shared__ int sc[256];
  sc[t] = s;
  __syncthreads();
  for (int off = 1; off < 256; off <<= 1) {
    int add = (t >= off) ? sc[t - off] : 0;
    __syncthreads();
    sc[t] += add;
    __syncthreads();
  }
  int run = sb[b] + sc[t] - s;
#pragma unroll
  for (int r = 0; r < 4; ++r) {
    int i = i0 + r;
    if (i < NN) { row_ptr[i] = run; cursor[i] = run; run += c[r]; }
  }
  if (b == 0 && t == 0) row_ptr[NN] = NE;
}

__global__ void fill_kernel(const int* __restrict__ rows, const int* __restrict__ cols,
                            int* __restrict__ cursor, int* __restrict__ csr_col) {
  int e = blockIdx.x * 256 + threadIdx.x;
  if (e < NE) {
    int r = rows[e];
    int pos = atomicAdd(&cursor[r], 1);
    csr_col[pos] = cols[e];
  }
}

// ---------------- aggregation v4: 8B/lane, 2 rows per load instr, 16 rows in flight ----------------
// y = bf16( dis[i] * (xs[i] + sum_nbr xs[c]) ).  One wave per node; halves sum disjoint
// row subsets, combined via shfl_xor(32).  fp32 accumulation (order differs from agg3:
// ~1e-7 rel, harmless).

__global__ __launch_bounds__(256) void agg4_kernel(const unsigned short* __restrict__ xsb,
    const int* __restrict__ row_ptr, const int* __restrict__ csr_col,
    const float* __restrict__ dis, unsigned short* __restrict__ y_bf) {
  const int t = threadIdx.x;
  const int n = blockIdx.x * 4 + (t >> 6);
  if (n >= NN) return;
  const int l    = t & 63;
  const int half = l >> 5;     // 0/1: which row of each pair this lane reads
  const int cl   = l & 31;     // uint2 index within the 256B row
  const uint2* xs2 = (const uint2*)xsb;

  float a0, a1, a2, a3;
  {  // self row: half 0 only (counted once)
    uint2 v = make_uint2(0u, 0u);
    if (half == 0) v = xs2[(size_t)n * 32 + cl];
    a0 = lo16f(v.x); a1 = hi16f(v.x);
    a2 = lo16f(v.y); a3 = hi16f(v.y);
  }

  const int s = row_ptr[n], e = row_ptr[n + 1];
  for (int j0 = s; j0 < e; j0 += 16) {
    int idx[8];
#pragma unroll
    for (int q = 0; q < 8; ++q) {
      int j = j0 + 2 * q + half;
      idx[q] = (j < e) ? csr_col[j] : -1;
    }
    uint2 ww[8];
#pragma unroll
    for (int q = 0; q < 8; ++q) {
      int r = (idx[q] < 0) ? 0 : idx[q];
      ww[q] = xs2[(size_t)r * 32 + cl];
    }
#pragma unroll
    for (int q = 0; q < 8; ++q) {
      if (idx[q] < 0) { ww[q].x = 0u; ww[q].y = 0u; }
      a0 += lo16f(ww[q].x); a1 += hi16f(ww[q].x);
      a2 += lo16f(ww[q].y); a3 += hi16f(ww[q].y);
    }
  }

  a0 += __shfl_xor(a0, 32);
  a1 += __shfl_xor(a1, 32);
  a2 += __shfl_xor(a2, 32);
  a3 += __shfl_xor(a3, 32);

  if (half == 0) {
    float dv = dis[n];
    uint2 o;
    o.x = (unsigned)f2bf(dv * a0) | ((unsigned)f2bf(dv * a1) << 16);
    o.y = (unsigned)f2bf(dv * a2) | ((unsigned)f2bf(dv * a3) << 16);
    ((uint2*)y_bf)[(size_t)n * 32 + cl] = o;
  }
}

// ---------------- split-bf16 MFMA GEMM: out_bf16 = epilogue(A[MxK] @ B[Kx128]) ----------------
// AF32=true (embed): A fp32 split in-register, 3 MFMAs/ktile (full fp32 accuracy).
// AF32=false (convs): A single bf16 plane, 2 MFMAs/ktile.
// MODE 0: v = dis[row]*(acc + bias)
// MODE 1: v = dis[row]*relu(BN(acc + bias))
// MODE 2: v = relu(BN(acc + bias))

template<int K, int MODE, bool AF32>
__global__ __launch_bounds__(256) void mfma_gemm(
    const float* __restrict__ Af,
    const unsigned short* __restrict__ Ab,
    const unsigned short* __restrict__ BThi, const unsigned short* __restrict__ BTlo,
    const float* __restrict__ bias, const float* __restrict__ dis,
    const float* __restrict__ g, const float* __restrict__ be,
    const float* __restrict__ mn, const float* __restrict__ vr,
    unsigned short* __restrict__ outb, int M) {
  const int tid  = threadIdx.x;
  const int lane = tid & 63;
  const int w    = tid >> 6;
  const int l15  = lane & 15;
  const int khi  = (lane >> 4) * 8;
  const int rowb = blockIdx.x * 128 + w * 32;

  int ar[2];
#pragma unroll
  for (int rt = 0; rt < 2; ++rt) {
    int r = rowb + rt * 16 + l15;
    ar[rt] = (r < M) ? r : M - 1;
  }

  f32x4 acc[2][8];
#pragma unroll
  for (int rt = 0; rt < 2; ++rt)
#pragma unroll
    for (int ct = 0; ct < 8; ++ct) acc[rt][ct] = (f32x4){0.f, 0.f, 0.f, 0.f};

#pragma unroll
  for (int kb = 0; kb < K; kb += 32) {
    short8 ahi[2], alo[2];
#pragma unroll
    for (int rt = 0; rt < 2; ++rt) {
      if constexpr (AF32) {
        const float* asrc = Af + (size_t)ar[rt] * K + kb + khi;
        float4 va0 = *(const float4*)(asrc);
        float4 va1 = *(const float4*)(asrc + 4);
        float av[8] = {va0.x, va0.y, va0.z, va0.w, va1.x, va1.y, va1.z, va1.w};
#pragma unroll
        for (int j = 0; j < 8; ++j) {
          unsigned short h = f2bf(av[j]);
          ahi[rt][j] = (short)h;
          alo[rt][j] = (short)f2bf(av[j] - bf2f(h));
        }
      } else {
        ahi[rt] = *(const short8*)(Ab + (size_t)ar[rt] * K + kb + khi);
      }
    }
#pragma unroll
    for (int ct = 0; ct < 8; ++ct) {
      size_t woff = (size_t)(ct * 16 + l15) * K + kb + khi;
      short8 bhi = *(const short8*)(BThi + woff);
      short8 blo = *(const short8*)(BTlo + woff);
#pragma unroll
      for (int rt = 0; rt < 2; ++rt) {
        acc[rt][ct] = __builtin_amdgcn_mfma_f32_16x16x32_bf16(ahi[rt], bhi, acc[rt][ct], 0, 0, 0);
        if constexpr (AF32)
          acc[rt][ct] = __builtin_amdgcn_mfma_f32_16x16x32_bf16(alo[rt], bhi, acc[rt][ct], 0, 0, 0);
        acc[rt][ct] = __builtin_amdgcn_mfma_f32_16x16x32_bf16(ahi[rt], blo, acc[rt][ct], 0, 0, 0);
      }
    }
  }

#pragma unroll
  for (int rt = 0; rt < 2; ++rt) {
    const int orow0 = rowb + rt * 16 + (lane >> 4) * 4;
    float dv[4];
    if constexpr (MODE != 2) {
#pragma unroll
      for (int r = 0; r < 4; ++r) dv[r] = (orow0 + r < M) ? dis[orow0 + r] : 0.f;
    }
#pragma unroll
    for (int ct = 0; ct < 8; ++ct) {
      int col = ct * 16 + l15;
      float bb = bias[col];
      float scale = 1.f, shift = 0.f;
      if constexpr (MODE >= 1) {
        float inv = rsqrtf(vr[col] + 1e-5f);
        scale = g[col] * inv;
        shift = be[col] - mn[col] * scale;
      }
#pragma unroll
      for (int r = 0; r < 4; ++r) {
        int orow = orow0 + r;
        if (orow < M) {
          float v = acc[rt][ct][r] + bb;
          if constexpr (MODE >= 1) v = fmaxf(v * scale + shift, 0.f);
          if constexpr (MODE != 2) v *= dv[r];
          outb[(size_t)orow * 128 + col] = f2bf(v);
        }
      }
    }
  }
}

// ---------------- MFMA pair MLP (round-9 proven structure) ----------------

__global__ __launch_bounds__(256, 3) void mlp2_kernel(
    const unsigned short* __restrict__ xb, const int* __restrict__ pairs,
    const unsigned short* __restrict__ pfb,
    const unsigned short* __restrict__ W1T, const float* __restrict__ b1,
    const unsigned short* __restrict__ W2T, const float* __restrict__ b2,
    const float* __restrict__ W3, const float* __restrict__ b3,
    float* __restrict__ out) {
  __shared__ unsigned short H1[128 * 136];

  const int tid  = threadIdx.x;
  const int lane = tid & 63;
  const int w    = tid >> 6;
  const int pb   = blockIdx.x * 128;
  const int rowbase = w * 32;
  const int l15  = lane & 15;
  const int khi  = (lane >> 4) * 8;
  const int rq   = (lane >> 4) * 4;

  int gp0 = pb + rowbase + l15;       if (gp0 >= NP) gp0 = NP - 1;
  int gp1 = pb + rowbase + 16 + l15;  if (gp1 >= NP) gp1 = NP - 1;
  const int2 pr0 = ((const int2*)pairs)[gp0];
  const int2 pr1 = ((const int2*)pairs)[gp1];

  short8 af[18];
#pragma unroll
  for (int kb = 0; kb < 4; ++kb) {
    af[kb]     = *(const short8*)(xb + (size_t)pr0.x * 128 + kb * 32 + khi);
    af[4 + kb] = *(const short8*)(xb + (size_t)pr0.y * 128 + kb * 32 + khi);
    af[9 + kb]     = *(const short8*)(xb + (size_t)pr1.x * 128 + kb * 32 + khi);
    af[9 + 4 + kb] = *(const short8*)(xb + (size_t)pr1.y * 128 + kb * 32 + khi);
  }
  af[8]  = *(const short8*)(pfb + (size_t)gp0 * 32 + khi);
  af[17] = *(const short8*)(pfb + (size_t)gp1 * 32 + khi);

  f32x4 acc[2][8];
#pragma unroll
  for (int p = 0; p < 2; ++p)
#pragma unroll
    for (int c = 0; c < 8; ++c) acc[p][c] = (f32x4){0.f, 0.f, 0.f, 0.f};

#pragma unroll
  for (int kb = 0; kb < 9; ++kb) {
    const unsigned short* wrow = W1T + (size_t)kb * 32 + khi;
#pragma unroll
    for (int ct = 0; ct < 8; ++ct) {
      short8 bfrag = *(const short8*)(wrow + (size_t)(ct * 16 + l15) * 288);
      acc[0][ct] = __builtin_amdgcn_mfma_f32_16x16x32_bf16(af[kb], bfrag, acc[0][ct], 0, 0, 0);
      acc[1][ct] = __builtin_amdgcn_mfma_f32_16x16x32_bf16(af[9 + kb], bfrag, acc[1][ct], 0, 0, 0);
    }
  }

#pragma unroll
  for (int ct = 0; ct < 8; ++ct) {
    float bv = b1[ct * 16 + l15];
    int col = ct * 16 + l15;
#pragma unroll
    for (int p = 0; p < 2; ++p) {
#pragma unroll
      for (int r = 0; r < 4; ++r) {
        int row = rowbase + p * 16 + rq + r;
        float v = fmaxf(acc[p][ct][r] + bv, 0.f);
        H1[row * 136 + col] = f2bf(v);
      }
    }
  }
  __syncthreads();

  f32x4 acc2[2][4];
#pragma unroll
  for (int p = 0; p < 2; ++p)
#pragma unroll
    for (int c = 0; c < 4; ++c) acc2[p][c] = (f32x4){0.f, 0.f, 0.f, 0.f};

#pragma unroll
  for (int kb = 0; kb < 4; ++kb) {
    int ko = kb * 32 + khi;
    short8 a0 = *(const short8*)&H1[(rowbase + l15) * 136 + ko];
    short8 a1 = *(const short8*)&H1[(rowbase + 16 + l15) * 136 + ko];
    const unsigned short* wrow = W2T + (size_t)ko;
#pragma unroll
    for (int ct = 0; ct < 4; ++ct) {
      short8 bfrag = *(const short8*)(wrow + (size_t)(ct * 16 + l15) * 128);
      acc2[0][ct] = __builtin_amdgcn_mfma_f32_16x16x32_bf16(a0, bfrag, acc2[0][ct], 0, 0, 0);
      acc2[1][ct] = __builtin_amdgcn_mfma_f32_16x16x32_bf16(a1, bfrag, acc2[1][ct], 0, 0, 0);
    }
  }

  float w3v[4], b2v[4];
#pragma unroll
  for (int ct = 0; ct < 4; ++ct) {
    w3v[ct] = W3[ct * 16 + l15];
    b2v[ct] = b2[ct * 16 + l15];
  }
  float b3v = b3[0];
#pragma unroll
  for (int p = 0; p < 2; ++p) {
#pragma unroll
    for (int r = 0; r < 4; ++r) {
      float s = 0.f;
#pragma unroll
      for (int ct = 0; ct < 4; ++ct) {
        float h2 = fmaxf(acc2[p][ct][r] + b2v[ct], 0.f);
        s += h2 * w3v[ct];
      }
      s += __shfl_xor(s, 1);
      s += __shfl_xor(s, 2);
      s += __shfl_xor(s, 4);
      s += __shfl_xor(s, 8);
      int row = pb + rowbase + p * 16 + rq + r;
      if (l15 == 0 && row < NP) out[row] = s + b3v;
    }
  }
}

// ---------------- launch ----------------

extern "C" void kernel_launch(void* const* d_in, const int* in_sizes, int n_in,
                              void* d_out, int out_size, void* d_ws, size_t ws_size,
                              hipStream_t stream) {
  (void)in_sizes; (void)n_in; (void)out_size; (void)ws_size;
  const float* atom  = (const float*)d_in[0];
  const int*   eidx  = (const int*)d_in[1];
  const int*   pairs = (const int*)d_in[2];
  const float* pfeat = (const float*)d_in[3];
  const float* embW  = (const float*)d_in[4];
  const float* embB  = (const float*)d_in[5];
  const float* convW = (const float*)d_in[6];
  const float* convB = (const float*)d_in[7];
  const float* bng   = (const float*)d_in[8];
  const float* bnb   = (const float*)d_in[9];
  const float* bnm   = (const float*)d_in[10];
  const float* bnv   = (const float*)d_in[11];
  const float* W1    = (const float*)d_in[12];
  const float* b1    = (const float*)d_in[13];
  const float* W2    = (const float*)d_in[14];
  const float* b2    = (const float*)d_in[15];
  const float* W3    = (const float*)d_in[16];
  const float* b3    = (const float*)d_in[17];
  float* out = (float*)d_out;

  uintptr_t base = (uintptr_t)d_ws;
  auto alloc = [&](size_t bytes) -> uintptr_t {
    uintptr_t p = base;
    base += (bytes + 255) & ~(size_t)255;
    return p;
  };
  int*   counts  = (int*)alloc((size_t)NN * 4);
  int*   row_ptr = (int*)alloc((size_t)(NN + 1) * 4);
  int*   cursor  = (int*)alloc((size_t)NN * 4);
  int*   csr_col = (int*)alloc((size_t)NE * 4);
  float* dis     = (float*)alloc((size_t)NN * 4);
  int*   bsum    = (int*)alloc(64 * 4);
  unsigned short* xs_bf = (unsigned short*)alloc((size_t)NN * 128 * 2);
  unsigned short* y_bf  = (unsigned short*)alloc((size_t)NN * 128 * 2);
  unsigned short* pf_bf = (unsigned short*)alloc((size_t)NP * 32 * 2);
  unsigned short* embT_hi  = (unsigned short*)alloc(8192 * 2);
  unsigned short* embT_lo  = (unsigned short*)alloc(8192 * 2);
  unsigned short* convT_hi = (unsigned short*)alloc(49152 * 2);
  unsigned short* convT_lo = (unsigned short*)alloc(49152 * 2);
  unsigned short* W1T      = (unsigned short*)alloc(36864 * 2);
  unsigned short* W2T      = (unsigned short*)alloc(8192 * 2);

  const int* erow = eidx;
  const int* ecol = eidx + NE;

  hipMemsetAsync(counts, 0, (size_t)NN * 4, stream);
  prep_all<<<PB_W + PB_CNT + PB_PF, 256, 0, stream>>>(
      embW, convW, W1, W2, erow, pfeat,
      embT_hi, embT_lo, convT_hi, convT_lo, W1T, W2T, counts, pf_bf);
  scan_partial_dis<<<NB_SCAN, 256, 0, stream>>>(counts, bsum, dis);
  scan_final<<<NB_SCAN, 256, 0, stream>>>(counts, bsum, row_ptr, cursor);
  fill_kernel<<<(NE + 255) / 256, 256, 0, stream>>>(erow, ecol, cursor, csr_col);

  // xs0 = bf16( dis * (atom @ embW + embB) )  -- split-A fp32 path
  mfma_gemm<64, 0, true><<<(NN + 127) / 128, 256, 0, stream>>>(
      atom, nullptr, embT_hi, embT_lo, embB, dis,
      nullptr, nullptr, nullptr, nullptr, xs_bf, NN);

  for (int l = 0; l < 3; ++l) {
    agg4_kernel<<<(NN + 3) / 4, 256, 0, stream>>>(xs_bf, row_ptr, csr_col, dis, y_bf);
    if (l < 2) {
      mfma_gemm<128, 1, false><<<(NN + 127) / 128, 256, 0, stream>>>(
          nullptr, y_bf,
          convT_hi + (size_t)l * 16384, convT_lo + (size_t)l * 16384,
          convB + (size_t)l * 128, dis,
          bng + (size_t)l * 128, bnb + (size_t)l * 128,
          bnm + (size_t)l * 128, bnv + (size_t)l * 128, xs_bf, NN);
    } else {
      mfma_gemm<128, 2, false><<<(NN + 127) / 128, 256, 0, stream>>>(
          nullptr, y_bf,
          convT_hi + (size_t)l * 16384, convT_lo + (size_t)l * 16384,
          convB + (size_t)l * 128, nullptr,
          bng + (size_t)l * 128, bnb + (size_t)l * 128,
          bnm + (size_t)l * 128, bnv + (size_t)l * 128, xs_bf, NN);
    }
  }

  mlp2_kernel<<<(NP + 127) / 128, 256, 0, stream>>>(xs_bf, pairs, pf_bf,
                                                    W1T, b1, W2T, b2, W3, b3, out);
}

// Round 11
// 323.258 us; speedup vs baseline: 1.0354x; 1.0354x over previous
//
#include <hip/hip_runtime.h>
#include <hip/hip_bf16.h>
#include <stdint.h>

#define NN 50000
#define NE 600000
#define NP 200000
#define SCAN_CHUNK 1024
#define NB_SCAN ((NN + SCAN_CHUNK - 1) / SCAN_CHUNK)   // 49

// prep_all block ranges
#define PB_W    400                          // weight prep: 102400 threads
#define PB_CNT  ((NE + 255) / 256)           // 2344
#define PB_PF   ((NP * 32 / 8 + 255) / 256)  // 3125

// fill_embed block ranges
#define FB_FILL ((NE + 255) / 256)           // 2344
#define FB_EMB  ((NN + 127) / 128)           // 391

typedef __attribute__((ext_vector_type(8))) short short8;
typedef __attribute__((ext_vector_type(4))) float f32x4;

static __device__ __forceinline__ unsigned short f2bf(float f) {
  union { float f; unsigned u; } a; a.f = f;
  unsigned r = a.u + 0x7fff + ((a.u >> 16) & 1);
  return (unsigned short)(r >> 16);
}
static __device__ __forceinline__ float bf2f(unsigned short h) {
  union { unsigned u; float f; } a; a.u = ((unsigned)h) << 16;
  return a.f;
}
static __device__ __forceinline__ float lo16f(unsigned w) {
  union { unsigned u; float f; } a; a.u = w << 16; return a.f;
}
static __device__ __forceinline__ float hi16f(unsigned w) {
  union { unsigned u; float f; } a; a.u = w & 0xffff0000u; return a.f;
}

// ---------------- fused prep: weight transpose + degree count + pf cast ----------------

__global__ __launch_bounds__(256) void prep_all(
    const float* __restrict__ embW, const float* __restrict__ convW,
    const float* __restrict__ W1, const float* __restrict__ W2,
    const int* __restrict__ erow, const float* __restrict__ pf,
    unsigned short* __restrict__ embT, unsigned short* __restrict__ convT,
    unsigned short* __restrict__ W1T, unsigned short* __restrict__ W2T,
    int* __restrict__ counts, unsigned short* __restrict__ pf_bf) {
  const int b = blockIdx.x, t = threadIdx.x;
  if (b < PB_W) {
    int idx = b * 256 + t;
    if (idx < 8192) {
      int n = idx >> 6, k = idx & 63;
      embT[idx] = f2bf(embW[(size_t)k * 128 + n]);
    } else if (idx < 8192 + 49152) {
      int i2 = idx - 8192;
      int l = i2 >> 14, n = (i2 >> 7) & 127, k = i2 & 127;
      convT[i2] = f2bf(convW[(size_t)l * 16384 + (size_t)k * 128 + n]);
    } else if (idx < 8192 + 49152 + 36864) {
      int i3 = idx - 57344;
      int n = i3 / 288, k = i3 % 288;
      W1T[i3] = f2bf(W1[(size_t)k * 128 + n]);
    } else if (idx < 8192 + 49152 + 36864 + 8192) {
      int i4 = idx - 94208;
      int n = i4 >> 7, k = i4 & 127;
      W2T[i4] = f2bf(W2[(size_t)k * 64 + n]);
    }
  } else if (b < PB_W + PB_CNT) {
    int e = (b - PB_W) * 256 + t;
    if (e < NE) atomicAdd(&counts[erow[e]], 1);
  } else {
    int i = (b - PB_W - PB_CNT) * 256 + t;   // group of 8 elements
    if (i < NP * 32 / 8) {
      const float4* s = (const float4*)(pf + (size_t)i * 8);
      float4 v0 = s[0], v1 = s[1];
      short8 o;
      o[0] = (short)f2bf(v0.x); o[1] = (short)f2bf(v0.y);
      o[2] = (short)f2bf(v0.z); o[3] = (short)f2bf(v0.w);
      o[4] = (short)f2bf(v1.x); o[5] = (short)f2bf(v1.y);
      o[6] = (short)f2bf(v1.z); o[7] = (short)f2bf(v1.w);
      *(short8*)(pf_bf + (size_t)i * 8) = o;
    }
  }
}

// ---------------- graph build ----------------

__global__ __launch_bounds__(256) void scan_partial_dis(const int* __restrict__ counts,
                                                        int* __restrict__ bsum,
                                                        float* __restrict__ dis) {
  const int b = blockIdx.x, t = threadIdx.x;
  const int base = b * SCAN_CHUNK;
  int s = 0;
  for (int j = t; j < SCAN_CHUNK; j += 256) {
    int i = base + j;
    if (i < NN) {
      int cv = counts[i];
      s += cv;
      dis[i] = rsqrtf((float)cv + 1.0f);
    }
  }
  __shared__ int red[4];
#pragma unroll
  for (int off = 32; off; off >>= 1) s += __shfl_down(s, off);
  if ((t & 63) == 0) red[t >> 6] = s;
  __syncthreads();
  if (t == 0) bsum[b] = red[0] + red[1] + red[2] + red[3];
}

__global__ __launch_bounds__(256) void scan_final(const int* __restrict__ counts,
                                                  const int* __restrict__ bsum,
                                                  int* __restrict__ row_ptr,
                                                  int* __restrict__ cursor) {
  const int b = blockIdx.x, t = threadIdx.x;
  __shared__ int sb[64];
  if (t < 64) {                       // wave 0: exclusive prefix of bsum[49]
    int v = (t < NB_SCAN) ? bsum[t] : 0;
    int orig = v;
#pragma unroll
    for (int off = 1; off < 64; off <<= 1) {
      int u = __shfl_up(v, off);
      if (t >= off) v += u;
    }
    sb[t] = v - orig;
  }
  const int i0 = b * SCAN_CHUNK + t * 4;
  int c[4]; int s = 0;
#pragma unroll
  for (int r = 0; r < 4; ++r) { int i = i0 + r; c[r] = (i < NN) ? counts[i] : 0; s += c[r]; }
  __shared__ int sc[256];
  sc[t] = s;
  __syncthreads();
  for (int off = 1; off < 256; off <<= 1) {
    int add = (t >= off) ? sc[t - off] : 0;
    __syncthreads();
    sc[t] += add;
    __syncthreads();
  }
  int run = sb[b] + sc[t] - s;
#pragma unroll
  for (int r = 0; r < 4; ++r) {
    int i = i0 + r;
    if (i < NN) { row_ptr[i] = run; cursor[i] = run; run += c[r]; }
  }
  if (b == 0 && t == 0) row_ptr[NN] = NE;
}

// ---------------- fused: CSR fill + embed GEMM ----------------
// blocks [0, FB_FILL): scatter edges into csr_col.
// blocks [FB_FILL, FB_FILL+FB_EMB): xs0 = bf16( dis * (atom @ embW + embB) ).
// embed: A fp32 split in-register (2 MFMAs: ahi*b + alo*b), B single bf16 plane.

__global__ __launch_bounds__(256) void fill_embed(
    const int* __restrict__ erow, const int* __restrict__ ecol,
    int* __restrict__ cursor, int* __restrict__ csr_col,
    const float* __restrict__ atom, const unsigned short* __restrict__ embT,
    const float* __restrict__ embB, const float* __restrict__ dis,
    unsigned short* __restrict__ outb) {
  const int b = blockIdx.x;
  if (b < FB_FILL) {
    int e = b * 256 + threadIdx.x;
    if (e < NE) {
      int r = erow[e];
      int pos = atomicAdd(&cursor[r], 1);
      csr_col[pos] = ecol[e];
    }
    return;
  }
  const int bid  = b - FB_FILL;
  const int K    = 64;
  const int tid  = threadIdx.x;
  const int lane = tid & 63;
  const int w    = tid >> 6;
  const int l15  = lane & 15;
  const int khi  = (lane >> 4) * 8;
  const int rowb = bid * 128 + w * 32;

  int ar[2];
#pragma unroll
  for (int rt = 0; rt < 2; ++rt) {
    int r = rowb + rt * 16 + l15;
    ar[rt] = (r < NN) ? r : NN - 1;
  }

  f32x4 acc[2][8];
#pragma unroll
  for (int rt = 0; rt < 2; ++rt)
#pragma unroll
    for (int ct = 0; ct < 8; ++ct) acc[rt][ct] = (f32x4){0.f, 0.f, 0.f, 0.f};

#pragma unroll
  for (int kb = 0; kb < K; kb += 32) {
    short8 ahi[2], alo[2];
#pragma unroll
    for (int rt = 0; rt < 2; ++rt) {
      const float* asrc = atom + (size_t)ar[rt] * K + kb + khi;
      float4 va0 = *(const float4*)(asrc);
      float4 va1 = *(const float4*)(asrc + 4);
      float av[8] = {va0.x, va0.y, va0.z, va0.w, va1.x, va1.y, va1.z, va1.w};
#pragma unroll
      for (int j = 0; j < 8; ++j) {
        unsigned short h = f2bf(av[j]);
        ahi[rt][j] = (short)h;
        alo[rt][j] = (short)f2bf(av[j] - bf2f(h));
      }
    }
#pragma unroll
    for (int ct = 0; ct < 8; ++ct) {
      short8 bfrag = *(const short8*)(embT + (size_t)(ct * 16 + l15) * K + kb + khi);
#pragma unroll
      for (int rt = 0; rt < 2; ++rt) {
        acc[rt][ct] = __builtin_amdgcn_mfma_f32_16x16x32_bf16(ahi[rt], bfrag, acc[rt][ct], 0, 0, 0);
        acc[rt][ct] = __builtin_amdgcn_mfma_f32_16x16x32_bf16(alo[rt], bfrag, acc[rt][ct], 0, 0, 0);
      }
    }
  }

#pragma unroll
  for (int rt = 0; rt < 2; ++rt) {
    const int orow0 = rowb + rt * 16 + (lane >> 4) * 4;
    float dv[4];
#pragma unroll
    for (int r = 0; r < 4; ++r) dv[r] = (orow0 + r < NN) ? dis[orow0 + r] : 0.f;
#pragma unroll
    for (int ct = 0; ct < 8; ++ct) {
      int col = ct * 16 + l15;
      float bb = embB[col];
#pragma unroll
      for (int r = 0; r < 4; ++r) {
        int orow = orow0 + r;
        if (orow < NN) {
          float v = (acc[rt][ct][r] + bb) * dv[r];
          outb[(size_t)orow * 128 + col] = f2bf(v);
        }
      }
    }
  }
}

// ---------------- aggregation v4 (round-10, perf == agg3, fewer instrs) ----------------

__global__ __launch_bounds__(256) void agg4_kernel(const unsigned short* __restrict__ xsb,
    const int* __restrict__ row_ptr, const int* __restrict__ csr_col,
    const float* __restrict__ dis, unsigned short* __restrict__ y_bf) {
  const int t = threadIdx.x;
  const int n = blockIdx.x * 4 + (t >> 6);
  if (n >= NN) return;
  const int l    = t & 63;
  const int half = l >> 5;
  const int cl   = l & 31;
  const uint2* xs2 = (const uint2*)xsb;

  float a0, a1, a2, a3;
  {
    uint2 v = make_uint2(0u, 0u);
    if (half == 0) v = xs2[(size_t)n * 32 + cl];
    a0 = lo16f(v.x); a1 = hi16f(v.x);
    a2 = lo16f(v.y); a3 = hi16f(v.y);
  }

  const int s = row_ptr[n], e = row_ptr[n + 1];
  for (int j0 = s; j0 < e; j0 += 16) {
    int idx[8];
#pragma unroll
    for (int q = 0; q < 8; ++q) {
      int j = j0 + 2 * q + half;
      idx[q] = (j < e) ? csr_col[j] : -1;
    }
    uint2 ww[8];
#pragma unroll
    for (int q = 0; q < 8; ++q) {
      int r = (idx[q] < 0) ? 0 : idx[q];
      ww[q] = xs2[(size_t)r * 32 + cl];
    }
#pragma unroll
    for (int q = 0; q < 8; ++q) {
      if (idx[q] < 0) { ww[q].x = 0u; ww[q].y = 0u; }
      a0 += lo16f(ww[q].x); a1 += hi16f(ww[q].x);
      a2 += lo16f(ww[q].y); a3 += hi16f(ww[q].y);
    }
  }

  a0 += __shfl_xor(a0, 32);
  a1 += __shfl_xor(a1, 32);
  a2 += __shfl_xor(a2, 32);
  a3 += __shfl_xor(a3, 32);

  if (half == 0) {
    float dv = dis[n];
    uint2 o;
    o.x = (unsigned)f2bf(dv * a0) | ((unsigned)f2bf(dv * a1) << 16);
    o.y = (unsigned)f2bf(dv * a2) | ((unsigned)f2bf(dv * a3) << 16);
    ((uint2*)y_bf)[(size_t)n * 32 + cl] = o;
  }
}

// ---------------- conv GEMM: single bf16 plane A and B, 1 MFMA/ktile ----------------
// MODE 1: v = dis[row]*relu(BN(acc+bias));  MODE 2: v = relu(BN(acc+bias))

template<int MODE>
__global__ __launch_bounds__(256) void conv_gemm(
    const unsigned short* __restrict__ Ab,
    const unsigned short* __restrict__ BT,
    const float* __restrict__ bias, const float* __restrict__ dis,
    const float* __restrict__ g, const float* __restrict__ be,
    const float* __restrict__ mn, const float* __restrict__ vr,
    unsigned short* __restrict__ outb) {
  const int K    = 128;
  const int tid  = threadIdx.x;
  const int lane = tid & 63;
  const int w    = tid >> 6;
  const int l15  = lane & 15;
  const int khi  = (lane >> 4) * 8;
  const int rowb = blockIdx.x * 128 + w * 32;

  int ar[2];
#pragma unroll
  for (int rt = 0; rt < 2; ++rt) {
    int r = rowb + rt * 16 + l15;
    ar[rt] = (r < NN) ? r : NN - 1;
  }

  f32x4 acc[2][8];
#pragma unroll
  for (int rt = 0; rt < 2; ++rt)
#pragma unroll
    for (int ct = 0; ct < 8; ++ct) acc[rt][ct] = (f32x4){0.f, 0.f, 0.f, 0.f};

#pragma unroll
  for (int kb = 0; kb < K; kb += 32) {
    short8 afr[2];
#pragma unroll
    for (int rt = 0; rt < 2; ++rt)
      afr[rt] = *(const short8*)(Ab + (size_t)ar[rt] * K + kb + khi);
#pragma unroll
    for (int ct = 0; ct < 8; ++ct) {
      short8 bfrag = *(const short8*)(BT + (size_t)(ct * 16 + l15) * K + kb + khi);
#pragma unroll
      for (int rt = 0; rt < 2; ++rt)
        acc[rt][ct] = __builtin_amdgcn_mfma_f32_16x16x32_bf16(afr[rt], bfrag, acc[rt][ct], 0, 0, 0);
    }
  }

#pragma unroll
  for (int rt = 0; rt < 2; ++rt) {
    const int orow0 = rowb + rt * 16 + (lane >> 4) * 4;
    float dv[4];
    if constexpr (MODE == 1) {
#pragma unroll
      for (int r = 0; r < 4; ++r) dv[r] = (orow0 + r < NN) ? dis[orow0 + r] : 0.f;
    }
#pragma unroll
    for (int ct = 0; ct < 8; ++ct) {
      int col = ct * 16 + l15;
      float bb = bias[col];
      float inv = rsqrtf(vr[col] + 1e-5f);
      float scale = g[col] * inv;
      float shift = be[col] - mn[col] * scale;
#pragma unroll
      for (int r = 0; r < 4; ++r) {
        int orow = orow0 + r;
        if (orow < NN) {
          float v = fmaxf((acc[rt][ct][r] + bb) * scale + shift, 0.f);
          if constexpr (MODE == 1) v *= dv[r];
          outb[(size_t)orow * 128 + col] = f2bf(v);
        }
      }
    }
  }
}

// ---------------- MFMA pair MLP (round-9/10 proven structure) ----------------

__global__ __launch_bounds__(256, 3) void mlp2_kernel(
    const unsigned short* __restrict__ xb, const int* __restrict__ pairs,
    const unsigned short* __restrict__ pfb,
    const unsigned short* __restrict__ W1T, const float* __restrict__ b1,
    const unsigned short* __restrict__ W2T, const float* __restrict__ b2,
    const float* __restrict__ W3, const float* __restrict__ b3,
    float* __restrict__ out) {
  __shared__ unsigned short H1[128 * 136];

  const int tid  = threadIdx.x;
  const int lane = tid & 63;
  const int w    = tid >> 6;
  const int pb   = blockIdx.x * 128;
  const int rowbase = w * 32;
  const int l15  = lane & 15;
  const int khi  = (lane >> 4) * 8;
  const int rq   = (lane >> 4) * 4;

  int gp0 = pb + rowbase + l15;       if (gp0 >= NP) gp0 = NP - 1;
  int gp1 = pb + rowbase + 16 + l15;  if (gp1 >= NP) gp1 = NP - 1;
  const int2 pr0 = ((const int2*)pairs)[gp0];
  const int2 pr1 = ((const int2*)pairs)[gp1];

  short8 af[18];
#pragma unroll
  for (int kb = 0; kb < 4; ++kb) {
    af[kb]     = *(const short8*)(xb + (size_t)pr0.x * 128 + kb * 32 + khi);
    af[4 + kb] = *(const short8*)(xb + (size_t)pr0.y * 128 + kb * 32 + khi);
    af[9 + kb]     = *(const short8*)(xb + (size_t)pr1.x * 128 + kb * 32 + khi);
    af[9 + 4 + kb] = *(const short8*)(xb + (size_t)pr1.y * 128 + kb * 32 + khi);
  }
  af[8]  = *(const short8*)(pfb + (size_t)gp0 * 32 + khi);
  af[17] = *(const short8*)(pfb + (size_t)gp1 * 32 + khi);

  f32x4 acc[2][8];
#pragma unroll
  for (int p = 0; p < 2; ++p)
#pragma unroll
    for (int c = 0; c < 8; ++c) acc[p][c] = (f32x4){0.f, 0.f, 0.f, 0.f};

#pragma unroll
  for (int kb = 0; kb < 9; ++kb) {
    const unsigned short* wrow = W1T + (size_t)kb * 32 + khi;
#pragma unroll
    for (int ct = 0; ct < 8; ++ct) {
      short8 bfrag = *(const short8*)(wrow + (size_t)(ct * 16 + l15) * 288);
      acc[0][ct] = __builtin_amdgcn_mfma_f32_16x16x32_bf16(af[kb], bfrag, acc[0][ct], 0, 0, 0);
      acc[1][ct] = __builtin_amdgcn_mfma_f32_16x16x32_bf16(af[9 + kb], bfrag, acc[1][ct], 0, 0, 0);
    }
  }

#pragma unroll
  for (int ct = 0; ct < 8; ++ct) {
    float bv = b1[ct * 16 + l15];
    int col = ct * 16 + l15;
#pragma unroll
    for (int p = 0; p < 2; ++p) {
#pragma unroll
      for (int r = 0; r < 4; ++r) {
        int row = rowbase + p * 16 + rq + r;
        float v = fmaxf(acc[p][ct][r] + bv, 0.f);
        H1[row * 136 + col] = f2bf(v);
      }
    }
  }
  __syncthreads();

  f32x4 acc2[2][4];
#pragma unroll
  for (int p = 0; p < 2; ++p)
#pragma unroll
    for (int c = 0; c < 4; ++c) acc2[p][c] = (f32x4){0.f, 0.f, 0.f, 0.f};

#pragma unroll
  for (int kb = 0; kb < 4; ++kb) {
    int ko = kb * 32 + khi;
    short8 a0 = *(const short8*)&H1[(rowbase + l15) * 136 + ko];
    short8 a1 = *(const short8*)&H1[(rowbase + 16 + l15) * 136 + ko];
    const unsigned short* wrow = W2T + (size_t)ko;
#pragma unroll
    for (int ct = 0; ct < 4; ++ct) {
      short8 bfrag = *(const short8*)(wrow + (size_t)(ct * 16 + l15) * 128);
      acc2[0][ct] = __builtin_amdgcn_mfma_f32_16x16x32_bf16(a0, bfrag, acc2[0][ct], 0, 0, 0);
      acc2[1][ct] = __builtin_amdgcn_mfma_f32_16x16x32_bf16(a1, bfrag, acc2[1][ct], 0, 0, 0);
    }
  }

  float w3v[4], b2v[4];
#pragma unroll
  for (int ct = 0; ct < 4; ++ct) {
    w3v[ct] = W3[ct * 16 + l15];
    b2v[ct] = b2[ct * 16 + l15];
  }
  float b3v = b3[0];
#pragma unroll
  for (int p = 0; p < 2; ++p) {
#pragma unroll
    for (int r = 0; r < 4; ++r) {
      float s = 0.f;
#pragma unroll
      for (int ct = 0; ct < 4; ++ct) {
        float h2 = fmaxf(acc2[p][ct][r] + b2v[ct], 0.f);
        s += h2 * w3v[ct];
      }
      s += __shfl_xor(s, 1);
      s += __shfl_xor(s, 2);
      s += __shfl_xor(s, 4);
      s += __shfl_xor(s, 8);
      int row = pb + rowbase + p * 16 + rq + r;
      if (l15 == 0 && row < NP) out[row] = s + b3v;
    }
  }
}

// ---------------- launch ----------------

extern "C" void kernel_launch(void* const* d_in, const int* in_sizes, int n_in,
                              void* d_out, int out_size, void* d_ws, size_t ws_size,
                              hipStream_t stream) {
  (void)in_sizes; (void)n_in; (void)out_size; (void)ws_size;
  const float* atom  = (const float*)d_in[0];
  const int*   eidx  = (const int*)d_in[1];
  const int*   pairs = (const int*)d_in[2];
  const float* pfeat = (const float*)d_in[3];
  const float* embW  = (const float*)d_in[4];
  const float* embB  = (const float*)d_in[5];
  const float* convW = (const float*)d_in[6];
  const float* convB = (const float*)d_in[7];
  const float* bng   = (const float*)d_in[8];
  const float* bnb   = (const float*)d_in[9];
  const float* bnm   = (const float*)d_in[10];
  const float* bnv   = (const float*)d_in[11];
  const float* W1    = (const float*)d_in[12];
  const float* b1    = (const float*)d_in[13];
  const float* W2    = (const float*)d_in[14];
  const float* b2    = (const float*)d_in[15];
  const float* W3    = (const float*)d_in[16];
  const float* b3    = (const float*)d_in[17];
  float* out = (float*)d_out;

  uintptr_t base = (uintptr_t)d_ws;
  auto alloc = [&](size_t bytes) -> uintptr_t {
    uintptr_t p = base;
    base += (bytes + 255) & ~(size_t)255;
    return p;
  };
  int*   counts  = (int*)alloc((size_t)NN * 4);
  int*   row_ptr = (int*)alloc((size_t)(NN + 1) * 4);
  int*   cursor  = (int*)alloc((size_t)NN * 4);
  int*   csr_col = (int*)alloc((size_t)NE * 4);
  float* dis     = (float*)alloc((size_t)NN * 4);
  int*   bsum    = (int*)alloc(64 * 4);
  unsigned short* xs_bf = (unsigned short*)alloc((size_t)NN * 128 * 2);
  unsigned short* y_bf  = (unsigned short*)alloc((size_t)NN * 128 * 2);
  unsigned short* pf_bf = (unsigned short*)alloc((size_t)NP * 32 * 2);
  unsigned short* embT  = (unsigned short*)alloc(8192 * 2);
  unsigned short* convT = (unsigned short*)alloc(49152 * 2);
  unsigned short* W1T   = (unsigned short*)alloc(36864 * 2);
  unsigned short* W2T   = (unsigned short*)alloc(8192 * 2);

  const int* erow = eidx;
  const int* ecol = eidx + NE;

  hipMemsetAsync(counts, 0, (size_t)NN * 4, stream);
  prep_all<<<PB_W + PB_CNT + PB_PF, 256, 0, stream>>>(
      embW, convW, W1, W2, erow, pfeat,
      embT, convT, W1T, W2T, counts, pf_bf);
  scan_partial_dis<<<NB_SCAN, 256, 0, stream>>>(counts, bsum, dis);
  scan_final<<<NB_SCAN, 256, 0, stream>>>(counts, bsum, row_ptr, cursor);

  // fused: CSR fill + embed GEMM (independent work, one dispatch)
  fill_embed<<<FB_FILL + FB_EMB, 256, 0, stream>>>(
      erow, ecol, cursor, csr_col, atom, embT, embB, dis, xs_bf);

  for (int l = 0; l < 3; ++l) {
    agg4_kernel<<<(NN + 3) / 4, 256, 0, stream>>>(xs_bf, row_ptr, csr_col, dis, y_bf);
    if (l < 2) {
      conv_gemm<1><<<(NN + 127) / 128, 256, 0, stream>>>(
          y_bf, convT + (size_t)l * 16384, convB + (size_t)l * 128, dis,
          bng + (size_t)l * 128, bnb + (size_t)l * 128,
          bnm + (size_t)l * 128, bnv + (size_t)l * 128, xs_bf);
    } else {
      conv_gemm<2><<<(NN + 127) / 128, 256, 0, stream>>>(
          y_bf, convT + (size_t)l * 16384, convB + (size_t)l * 128, nullptr,
          bng + (size_t)l * 128, bnb + (size_t)l * 128,
          bnm + (size_t)l * 128, bnv + (size_t)l * 128, xs_bf);
    }
  }

  mlp2_kernel<<<(NP + 127) / 128, 256, 0, stream>>>(xs_bf, pairs, pf_bf,
                                                    W1T, b1, W2T, b2, W3, b3, out);
}

// Round 12
// 289.989 us; speedup vs baseline: 1.1542x; 1.1147x over previous
//
#include <hip/hip_runtime.h>
#include <hip/hip_bf16.h>
#include <stdint.h>

#define NN 50000
#define NE 600000
#define NP 200000
#define SCAN_CHUNK 1024
#define NB_SCAN ((NN + SCAN_CHUNK - 1) / SCAN_CHUNK)   // 49

// bucketed CSR build
#define NBUK 49            // node buckets of 1024 (50000 >> 10 -> 0..48)
#define BCAP 16384         // staging capacity per bucket (mean 12.2K, >30 sigma slack)
#define EPB  2048          // edges per pass-1 block
#define PB_BKT ((NE + EPB - 1) / EPB)        // 293

// prep_all block ranges
#define PB_W    400                          // weight prep: 102400 threads
#define PB_CNT  ((NE + 255) / 256)           // 2344
#define PB_PF   ((NP * 32 / 8 + 255) / 256)  // 3125

// csr_embed block ranges
#define CB_CSR NBUK                          // 49
#define CB_EMB ((NN + 127) / 128)            // 391

typedef __attribute__((ext_vector_type(8))) short short8;
typedef __attribute__((ext_vector_type(4))) float f32x4;

static __device__ __forceinline__ unsigned short f2bf(float f) {
  union { float f; unsigned u; } a; a.f = f;
  unsigned r = a.u + 0x7fff + ((a.u >> 16) & 1);
  return (unsigned short)(r >> 16);
}
static __device__ __forceinline__ float bf2f(unsigned short h) {
  union { unsigned u; float f; } a; a.u = ((unsigned)h) << 16;
  return a.f;
}
static __device__ __forceinline__ float lo16f(unsigned w) {
  union { unsigned u; float f; } a; a.u = w << 16; return a.f;
}
static __device__ __forceinline__ float hi16f(unsigned w) {
  union { unsigned u; float f; } a; a.u = w & 0xffff0000u; return a.f;
}

// ---------------- fused prep: weights + degree count + pf cast + edge bucketing ----------------

__global__ __launch_bounds__(256) void prep_all(
    const float* __restrict__ embW, const float* __restrict__ convW,
    const float* __restrict__ W1, const float* __restrict__ W2,
    const int* __restrict__ erow, const int* __restrict__ ecol,
    const float* __restrict__ pf,
    unsigned short* __restrict__ embT, unsigned short* __restrict__ convT,
    unsigned short* __restrict__ W1T, unsigned short* __restrict__ W2T,
    int* __restrict__ counts, unsigned short* __restrict__ pf_bf,
    int* __restrict__ bcur, unsigned* __restrict__ staging) {
  const int b = blockIdx.x, t = threadIdx.x;
  if (b < PB_W) {
    int idx = b * 256 + t;
    if (idx < 8192) {
      int n = idx >> 6, k = idx & 63;
      embT[idx] = f2bf(embW[(size_t)k * 128 + n]);
    } else if (idx < 8192 + 49152) {
      int i2 = idx - 8192;
      int l = i2 >> 14, n = (i2 >> 7) & 127, k = i2 & 127;
      convT[i2] = f2bf(convW[(size_t)l * 16384 + (size_t)k * 128 + n]);
    } else if (idx < 8192 + 49152 + 36864) {
      int i3 = idx - 57344;
      int n = i3 / 288, k = i3 % 288;
      W1T[i3] = f2bf(W1[(size_t)k * 128 + n]);
    } else if (idx < 8192 + 49152 + 36864 + 8192) {
      int i4 = idx - 94208;
      int n = i4 >> 7, k = i4 & 127;
      W2T[i4] = f2bf(W2[(size_t)k * 64 + n]);
    }
  } else if (b < PB_W + PB_CNT) {
    int e = (b - PB_W) * 256 + t;
    if (e < NE) atomicAdd(&counts[erow[e]], 1);
  } else if (b < PB_W + PB_CNT + PB_PF) {
    int i = (b - PB_W - PB_CNT) * 256 + t;   // group of 8 elements
    if (i < NP * 32 / 8) {
      const float4* s = (const float4*)(pf + (size_t)i * 8);
      float4 v0 = s[0], v1 = s[1];
      short8 o;
      o[0] = (short)f2bf(v0.x); o[1] = (short)f2bf(v0.y);
      o[2] = (short)f2bf(v0.z); o[3] = (short)f2bf(v0.w);
      o[4] = (short)f2bf(v1.x); o[5] = (short)f2bf(v1.y);
      o[6] = (short)f2bf(v1.z); o[7] = (short)f2bf(v1.w);
      *(short8*)(pf_bf + (size_t)i * 8) = o;
    }
  } else {
    // ---- bucket pass 1: partition edges into 49 node-range buckets, coalesced ----
    __shared__ int hist[NBUK];
    __shared__ int base[NBUK];
    const int bb = b - (PB_W + PB_CNT + PB_PF);
    const int e0 = bb * EPB;
    for (int i = t; i < NBUK; i += 256) hist[i] = 0;
    __syncthreads();
    int rr[8], cc8[8], off8[8];
#pragma unroll
    for (int q = 0; q < 8; ++q) {
      int e = e0 + q * 256 + t;
      rr[q] = -1;
      if (e < NE) {
        rr[q] = erow[e];
        cc8[q] = ecol[e];
        off8[q] = atomicAdd(&hist[rr[q] >> 10], 1);
      }
    }
    __syncthreads();
    for (int i = t; i < NBUK; i += 256) base[i] = atomicAdd(&bcur[i], hist[i]);
    __syncthreads();
#pragma unroll
    for (int q = 0; q < 8; ++q) {
      if (rr[q] >= 0) {
        int bk = rr[q] >> 10;
        staging[(size_t)bk * BCAP + base[bk] + off8[q]] =
            ((unsigned)rr[q] << 16) | (unsigned)cc8[q];
      }
    }
  }
}

// ---------------- graph scan ----------------

__global__ __launch_bounds__(256) void scan_partial_dis(const int* __restrict__ counts,
                                                        int* __restrict__ bsum,
                                                        float* __restrict__ dis) {
  const int b = blockIdx.x, t = threadIdx.x;
  const int base = b * SCAN_CHUNK;
  int s = 0;
  for (int j = t; j < SCAN_CHUNK; j += 256) {
    int i = base + j;
    if (i < NN) {
      int cv = counts[i];
      s += cv;
      dis[i] = rsqrtf((float)cv + 1.0f);
    }
  }
  __shared__ int red[4];
#pragma unroll
  for (int off = 32; off; off >>= 1) s += __shfl_down(s, off);
  if ((t & 63) == 0) red[t >> 6] = s;
  __syncthreads();
  if (t == 0) bsum[b] = red[0] + red[1] + red[2] + red[3];
}

__global__ __launch_bounds__(256) void scan_final(const int* __restrict__ counts,
                                                  const int* __restrict__ bsum,
                                                  int* __restrict__ row_ptr) {
  const int b = blockIdx.x, t = threadIdx.x;
  __shared__ int sb[64];
  if (t < 64) {                       // wave 0: exclusive prefix of bsum[49]
    int v = (t < NB_SCAN) ? bsum[t] : 0;
    int orig = v;
#pragma unroll
    for (int off = 1; off < 64; off <<= 1) {
      int u = __shfl_up(v, off);
      if (t >= off) v += u;
    }
    sb[t] = v - orig;
  }
  const int i0 = b * SCAN_CHUNK + t * 4;
  int c[4]; int s = 0;
#pragma unroll
  for (int r = 0; r < 4; ++r) { int i = i0 + r; c[r] = (i < NN) ? counts[i] : 0; s += c[r]; }
  __shared__ int sc[256];
  sc[t] = s;
  __syncthreads();
  for (int off = 1; off < 256; off <<= 1) {
    int add = (t >= off) ? sc[t - off] : 0;
    __syncthreads();
    sc[t] += add;
    __syncthreads();
  }
  int run = sb[b] + sc[t] - s;
#pragma unroll
  for (int r = 0; r < 4; ++r) {
    int i = i0 + r;
    if (i < NN) { row_ptr[i] = run; run += c[r]; }
  }
  if (b == 0 && t == 0) row_ptr[NN] = NE;
}

// ---------------- fused: bucket pass 2 (CSR segment build, coalesced) + embed GEMM ----------------
// blocks [0, CB_CSR): scatter staged bucket edges into an LDS csr image, write out coalesced.
// blocks [CB_CSR, CB_CSR+CB_EMB): xs0 = bf16( dis * (atom @ embW + embB) ).

__global__ __launch_bounds__(256) void csr_embed(
    const int* __restrict__ bcur, const unsigned* __restrict__ staging,
    const int* __restrict__ row_ptr, int* __restrict__ csr_col,
    const float* __restrict__ atom, const unsigned short* __restrict__ embT,
    const float* __restrict__ embB, const float* __restrict__ dis,
    unsigned short* __restrict__ outb) {
  if (blockIdx.x < CB_CSR) {
    __shared__ unsigned short lcsr[BCAP];   // 32 KB: csr segment image (u16 cols)
    __shared__ int lcur[1024];              // 4 KB: per-node local cursors
    const int bk = blockIdx.x, t = threadIdx.x;
    const int lo = bk << 10;
    const int hi = (lo + 1024 < NN) ? lo + 1024 : NN;
    const int segbase = row_ptr[lo];
    for (int n = lo + t; n < hi; n += 256) lcur[n - lo] = row_ptr[n] - segbase;
    __syncthreads();
    const int cnt = bcur[bk];
    const unsigned* st = staging + (size_t)bk * BCAP;
    for (int j = t; j < cnt; j += 256) {
      unsigned rc = st[j];
      int pos = atomicAdd(&lcur[(rc >> 16) - lo], 1);
      lcsr[pos] = (unsigned short)(rc & 0xFFFFu);
    }
    __syncthreads();
    const int seglen = row_ptr[hi] - segbase;
    for (int j = t; j < seglen; j += 256)
      csr_col[segbase + j] = (int)lcsr[j];
    return;
  }
  // ---- embed: A fp32 split in-register (2 MFMAs), B single bf16 plane ----
  const int bid  = blockIdx.x - CB_CSR;
  const int K    = 64;
  const int tid  = threadIdx.x;
  const int lane = tid & 63;
  const int w    = tid >> 6;
  const int l15  = lane & 15;
  const int khi  = (lane >> 4) * 8;
  const int rowb = bid * 128 + w * 32;

  int ar[2];
#pragma unroll
  for (int rt = 0; rt < 2; ++rt) {
    int r = rowb + rt * 16 + l15;
    ar[rt] = (r < NN) ? r : NN - 1;
  }

  f32x4 acc[2][8];
#pragma unroll
  for (int rt = 0; rt < 2; ++rt)
#pragma unroll
    for (int ct = 0; ct < 8; ++ct) acc[rt][ct] = (f32x4){0.f, 0.f, 0.f, 0.f};

#pragma unroll
  for (int kb = 0; kb < K; kb += 32) {
    short8 ahi[2], alo[2];
#pragma unroll
    for (int rt = 0; rt < 2; ++rt) {
      const float* asrc = atom + (size_t)ar[rt] * K + kb + khi;
      float4 va0 = *(const float4*)(asrc);
      float4 va1 = *(const float4*)(asrc + 4);
      float av[8] = {va0.x, va0.y, va0.z, va0.w, va1.x, va1.y, va1.z, va1.w};
#pragma unroll
      for (int j = 0; j < 8; ++j) {
        unsigned short h = f2bf(av[j]);
        ahi[rt][j] = (short)h;
        alo[rt][j] = (short)f2bf(av[j] - bf2f(h));
      }
    }
#pragma unroll
    for (int ct = 0; ct < 8; ++ct) {
      short8 bfrag = *(const short8*)(embT + (size_t)(ct * 16 + l15) * K + kb + khi);
#pragma unroll
      for (int rt = 0; rt < 2; ++rt) {
        acc[rt][ct] = __builtin_amdgcn_mfma_f32_16x16x32_bf16(ahi[rt], bfrag, acc[rt][ct], 0, 0, 0);
        acc[rt][ct] = __builtin_amdgcn_mfma_f32_16x16x32_bf16(alo[rt], bfrag, acc[rt][ct], 0, 0, 0);
      }
    }
  }

#pragma unroll
  for (int rt = 0; rt < 2; ++rt) {
    const int orow0 = rowb + rt * 16 + (lane >> 4) * 4;
    float dv[4];
#pragma unroll
    for (int r = 0; r < 4; ++r) dv[r] = (orow0 + r < NN) ? dis[orow0 + r] : 0.f;
#pragma unroll
    for (int ct = 0; ct < 8; ++ct) {
      int col = ct * 16 + l15;
      float bb = embB[col];
#pragma unroll
      for (int r = 0; r < 4; ++r) {
        int orow = orow0 + r;
        if (orow < NN) {
          float v = (acc[rt][ct][r] + bb) * dv[r];
          outb[(size_t)orow * 128 + col] = f2bf(v);
        }
      }
    }
  }
}

// ---------------- aggregation v4 (round-10/11 proven) ----------------

__global__ __launch_bounds__(256) void agg4_kernel(const unsigned short* __restrict__ xsb,
    const int* __restrict__ row_ptr, const int* __restrict__ csr_col,
    const float* __restrict__ dis, unsigned short* __restrict__ y_bf) {
  const int t = threadIdx.x;
  const int n = blockIdx.x * 4 + (t >> 6);
  if (n >= NN) return;
  const int l    = t & 63;
  const int half = l >> 5;
  const int cl   = l & 31;
  const uint2* xs2 = (const uint2*)xsb;

  float a0, a1, a2, a3;
  {
    uint2 v = make_uint2(0u, 0u);
    if (half == 0) v = xs2[(size_t)n * 32 + cl];
    a0 = lo16f(v.x); a1 = hi16f(v.x);
    a2 = lo16f(v.y); a3 = hi16f(v.y);
  }

  const int s = row_ptr[n], e = row_ptr[n + 1];
  for (int j0 = s; j0 < e; j0 += 16) {
    int idx[8];
#pragma unroll
    for (int q = 0; q < 8; ++q) {
      int j = j0 + 2 * q + half;
      idx[q] = (j < e) ? csr_col[j] : -1;
    }
    uint2 ww[8];
#pragma unroll
    for (int q = 0; q < 8; ++q) {
      int r = (idx[q] < 0) ? 0 : idx[q];
      ww[q] = xs2[(size_t)r * 32 + cl];
    }
#pragma unroll
    for (int q = 0; q < 8; ++q) {
      if (idx[q] < 0) { ww[q].x = 0u; ww[q].y = 0u; }
      a0 += lo16f(ww[q].x); a1 += hi16f(ww[q].x);
      a2 += lo16f(ww[q].y); a3 += hi16f(ww[q].y);
    }
  }

  a0 += __shfl_xor(a0, 32);
  a1 += __shfl_xor(a1, 32);
  a2 += __shfl_xor(a2, 32);
  a3 += __shfl_xor(a3, 32);

  if (half == 0) {
    float dv = dis[n];
    uint2 o;
    o.x = (unsigned)f2bf(dv * a0) | ((unsigned)f2bf(dv * a1) << 16);
    o.y = (unsigned)f2bf(dv * a2) | ((unsigned)f2bf(dv * a3) << 16);
    ((uint2*)y_bf)[(size_t)n * 32 + cl] = o;
  }
}

// ---------------- conv GEMM: single bf16 plane A and B, 1 MFMA/ktile ----------------

template<int MODE>
__global__ __launch_bounds__(256) void conv_gemm(
    const unsigned short* __restrict__ Ab,
    const unsigned short* __restrict__ BT,
    const float* __restrict__ bias, const float* __restrict__ dis,
    const float* __restrict__ g, const float* __restrict__ be,
    const float* __restrict__ mn, const float* __restrict__ vr,
    unsigned short* __restrict__ outb) {
  const int K    = 128;
  const int tid  = threadIdx.x;
  const int lane = tid & 63;
  const int w    = tid >> 6;
  const int l15  = lane & 15;
  const int khi  = (lane >> 4) * 8;
  const int rowb = blockIdx.x * 128 + w * 32;

  int ar[2];
#pragma unroll
  for (int rt = 0; rt < 2; ++rt) {
    int r = rowb + rt * 16 + l15;
    ar[rt] = (r < NN) ? r : NN - 1;
  }

  f32x4 acc[2][8];
#pragma unroll
  for (int rt = 0; rt < 2; ++rt)
#pragma unroll
    for (int ct = 0; ct < 8; ++ct) acc[rt][ct] = (f32x4){0.f, 0.f, 0.f, 0.f};

#pragma unroll
  for (int kb = 0; kb < K; kb += 32) {
    short8 afr[2];
#pragma unroll
    for (int rt = 0; rt < 2; ++rt)
      afr[rt] = *(const short8*)(Ab + (size_t)ar[rt] * K + kb + khi);
#pragma unroll
    for (int ct = 0; ct < 8; ++ct) {
      short8 bfrag = *(const short8*)(BT + (size_t)(ct * 16 + l15) * K + kb + khi);
#pragma unroll
      for (int rt = 0; rt < 2; ++rt)
        acc[rt][ct] = __builtin_amdgcn_mfma_f32_16x16x32_bf16(afr[rt], bfrag, acc[rt][ct], 0, 0, 0);
    }
  }

#pragma unroll
  for (int rt = 0; rt < 2; ++rt) {
    const int orow0 = rowb + rt * 16 + (lane >> 4) * 4;
    float dv[4];
    if constexpr (MODE == 1) {
#pragma unroll
      for (int r = 0; r < 4; ++r) dv[r] = (orow0 + r < NN) ? dis[orow0 + r] : 0.f;
    }
#pragma unroll
    for (int ct = 0; ct < 8; ++ct) {
      int col = ct * 16 + l15;
      float bb = bias[col];
      float inv = rsqrtf(vr[col] + 1e-5f);
      float scale = g[col] * inv;
      float shift = be[col] - mn[col] * scale;
#pragma unroll
      for (int r = 0; r < 4; ++r) {
        int orow = orow0 + r;
        if (orow < NN) {
          float v = fmaxf((acc[rt][ct][r] + bb) * scale + shift, 0.f);
          if constexpr (MODE == 1) v *= dv[r];
          outb[(size_t)orow * 128 + col] = f2bf(v);
        }
      }
    }
  }
}

// ---------------- MFMA pair MLP (proven structure) ----------------

__global__ __launch_bounds__(256, 3) void mlp2_kernel(
    const unsigned short* __restrict__ xb, const int* __restrict__ pairs,
    const unsigned short* __restrict__ pfb,
    const unsigned short* __restrict__ W1T, const float* __restrict__ b1,
    const unsigned short* __restrict__ W2T, const float* __restrict__ b2,
    const float* __restrict__ W3, const float* __restrict__ b3,
    float* __restrict__ out) {
  __shared__ unsigned short H1[128 * 136];

  const int tid  = threadIdx.x;
  const int lane = tid & 63;
  const int w    = tid >> 6;
  const int pb   = blockIdx.x * 128;
  const int rowbase = w * 32;
  const int l15  = lane & 15;
  const int khi  = (lane >> 4) * 8;
  const int rq   = (lane >> 4) * 4;

  int gp0 = pb + rowbase + l15;       if (gp0 >= NP) gp0 = NP - 1;
  int gp1 = pb + rowbase + 16 + l15;  if (gp1 >= NP) gp1 = NP - 1;
  const int2 pr0 = ((const int2*)pairs)[gp0];
  const int2 pr1 = ((const int2*)pairs)[gp1];

  short8 af[18];
#pragma unroll
  for (int kb = 0; kb < 4; ++kb) {
    af[kb]     = *(const short8*)(xb + (size_t)pr0.x * 128 + kb * 32 + khi);
    af[4 + kb] = *(const short8*)(xb + (size_t)pr0.y * 128 + kb * 32 + khi);
    af[9 + kb]     = *(const short8*)(xb + (size_t)pr1.x * 128 + kb * 32 + khi);
    af[9 + 4 + kb] = *(const short8*)(xb + (size_t)pr1.y * 128 + kb * 32 + khi);
  }
  af[8]  = *(const short8*)(pfb + (size_t)gp0 * 32 + khi);
  af[17] = *(const short8*)(pfb + (size_t)gp1 * 32 + khi);

  f32x4 acc[2][8];
#pragma unroll
  for (int p = 0; p < 2; ++p)
#pragma unroll
    for (int c = 0; c < 8; ++c) acc[p][c] = (f32x4){0.f, 0.f, 0.f, 0.f};

#pragma unroll
  for (int kb = 0; kb < 9; ++kb) {
    const unsigned short* wrow = W1T + (size_t)kb * 32 + khi;
#pragma unroll
    for (int ct = 0; ct < 8; ++ct) {
      short8 bfrag = *(const short8*)(wrow + (size_t)(ct * 16 + l15) * 288);
      acc[0][ct] = __builtin_amdgcn_mfma_f32_16x16x32_bf16(af[kb], bfrag, acc[0][ct], 0, 0, 0);
      acc[1][ct] = __builtin_amdgcn_mfma_f32_16x16x32_bf16(af[9 + kb], bfrag, acc[1][ct], 0, 0, 0);
    }
  }

#pragma unroll
  for (int ct = 0; ct < 8; ++ct) {
    float bv = b1[ct * 16 + l15];
    int col = ct * 16 + l15;
#pragma unroll
    for (int p = 0; p < 2; ++p) {
#pragma unroll
      for (int r = 0; r < 4; ++r) {
        int row = rowbase + p * 16 + rq + r;
        float v = fmaxf(acc[p][ct][r] + bv, 0.f);
        H1[row * 136 + col] = f2bf(v);
      }
    }
  }
  __syncthreads();

  f32x4 acc2[2][4];
#pragma unroll
  for (int p = 0; p < 2; ++p)
#pragma unroll
    for (int c = 0; c < 4; ++c) acc2[p][c] = (f32x4){0.f, 0.f, 0.f, 0.f};

#pragma unroll
  for (int kb = 0; kb < 4; ++kb) {
    int ko = kb * 32 + khi;
    short8 a0 = *(const short8*)&H1[(rowbase + l15) * 136 + ko];
    short8 a1 = *(const short8*)&H1[(rowbase + 16 + l15) * 136 + ko];
    const unsigned short* wrow = W2T + (size_t)ko;
#pragma unroll
    for (int ct = 0; ct < 4; ++ct) {
      short8 bfrag = *(const short8*)(wrow + (size_t)(ct * 16 + l15) * 128);
      acc2[0][ct] = __builtin_amdgcn_mfma_f32_16x16x32_bf16(a0, bfrag, acc2[0][ct], 0, 0, 0);
      acc2[1][ct] = __builtin_amdgcn_mfma_f32_16x16x32_bf16(a1, bfrag, acc2[1][ct], 0, 0, 0);
    }
  }

  float w3v[4], b2v[4];
#pragma unroll
  for (int ct = 0; ct < 4; ++ct) {
    w3v[ct] = W3[ct * 16 + l15];
    b2v[ct] = b2[ct * 16 + l15];
  }
  float b3v = b3[0];
#pragma unroll
  for (int p = 0; p < 2; ++p) {
#pragma unroll
    for (int r = 0; r < 4; ++r) {
      float s = 0.f;
#pragma unroll
      for (int ct = 0; ct < 4; ++ct) {
        float h2 = fmaxf(acc2[p][ct][r] + b2v[ct], 0.f);
        s += h2 * w3v[ct];
      }
      s += __shfl_xor(s, 1);
      s += __shfl_xor(s, 2);
      s += __shfl_xor(s, 4);
      s += __shfl_xor(s, 8);
      int row = pb + rowbase + p * 16 + rq + r;
      if (l15 == 0 && row < NP) out[row] = s + b3v;
    }
  }
}

// ---------------- launch ----------------

extern "C" void kernel_launch(void* const* d_in, const int* in_sizes, int n_in,
                              void* d_out, int out_size, void* d_ws, size_t ws_size,
                              hipStream_t stream) {
  (void)in_sizes; (void)n_in; (void)out_size; (void)ws_size;
  const float* atom  = (const float*)d_in[0];
  const int*   eidx  = (const int*)d_in[1];
  const int*   pairs = (const int*)d_in[2];
  const float* pfeat = (const float*)d_in[3];
  const float* embW  = (const float*)d_in[4];
  const float* embB  = (const float*)d_in[5];
  const float* convW = (const float*)d_in[6];
  const float* convB = (const float*)d_in[7];
  const float* bng   = (const float*)d_in[8];
  const float* bnb   = (const float*)d_in[9];
  const float* bnm   = (const float*)d_in[10];
  const float* bnv   = (const float*)d_in[11];
  const float* W1    = (const float*)d_in[12];
  const float* b1    = (const float*)d_in[13];
  const float* W2    = (const float*)d_in[14];
  const float* b2    = (const float*)d_in[15];
  const float* W3    = (const float*)d_in[16];
  const float* b3    = (const float*)d_in[17];
  float* out = (float*)d_out;

  uintptr_t base = (uintptr_t)d_ws;
  auto alloc = [&](size_t bytes) -> uintptr_t {
    uintptr_t p = base;
    base += (bytes + 255) & ~(size_t)255;
    return p;
  };
  int*      counts  = (int*)alloc((size_t)NN * 4);
  int*      row_ptr = (int*)alloc((size_t)(NN + 1) * 4);
  int*      csr_col = (int*)alloc((size_t)NE * 4);
  float*    dis     = (float*)alloc((size_t)NN * 4);
  int*      bsum    = (int*)alloc(64 * 4);
  int*      bcur    = (int*)alloc(64 * 4);
  unsigned* staging = (unsigned*)alloc((size_t)NBUK * BCAP * 4);
  unsigned short* xs_bf = (unsigned short*)alloc((size_t)NN * 128 * 2);
  unsigned short* y_bf  = (unsigned short*)alloc((size_t)NN * 128 * 2);
  unsigned short* pf_bf = (unsigned short*)alloc((size_t)NP * 32 * 2);
  unsigned short* embT  = (unsigned short*)alloc(8192 * 2);
  unsigned short* convT = (unsigned short*)alloc(49152 * 2);
  unsigned short* W1T   = (unsigned short*)alloc(36864 * 2);
  unsigned short* W2T   = (unsigned short*)alloc(8192 * 2);

  const int* erow = eidx;
  const int* ecol = eidx + NE;

  hipMemsetAsync(counts, 0, (size_t)NN * 4, stream);
  hipMemsetAsync(bcur, 0, 64 * 4, stream);
  prep_all<<<PB_W + PB_CNT + PB_PF + PB_BKT, 256, 0, stream>>>(
      embW, convW, W1, W2, erow, ecol, pfeat,
      embT, convT, W1T, W2T, counts, pf_bf, bcur, staging);
  scan_partial_dis<<<NB_SCAN, 256, 0, stream>>>(counts, bsum, dis);
  scan_final<<<NB_SCAN, 256, 0, stream>>>(counts, bsum, row_ptr);

  // fused: coalesced CSR segment build + embed GEMM
  csr_embed<<<CB_CSR + CB_EMB, 256, 0, stream>>>(
      bcur, staging, row_ptr, csr_col, atom, embT, embB, dis, xs_bf);

  for (int l = 0; l < 3; ++l) {
    agg4_kernel<<<(NN + 3) / 4, 256, 0, stream>>>(xs_bf, row_ptr, csr_col, dis, y_bf);
    if (l < 2) {
      conv_gemm<1><<<(NN + 127) / 128, 256, 0, stream>>>(
          y_bf, convT + (size_t)l * 16384, convB + (size_t)l * 128, dis,
          bng + (size_t)l * 128, bnb + (size_t)l * 128,
          bnm + (size_t)l * 128, bnv + (size_t)l * 128, xs_bf);
    } else {
      conv_gemm<2><<<(NN + 127) / 128, 256, 0, stream>>>(
          y_bf, convT + (size_t)l * 16384, convB + (size_t)l * 128, nullptr,
          bng + (size_t)l * 128, bnb + (size_t)l * 128,
          bnm + (size_t)l * 128, bnv + (size_t)l * 128, xs_bf);
    }
  }

  mlp2_kernel<<<(NP + 127) / 128, 256, 0, stream>>>(xs_bf, pairs, pf_bf,
                                                    W1T, b1, W2T, b2, W3, b3, out);
}

// Round 13
// 286.982 us; speedup vs baseline: 1.1663x; 1.0105x over previous
//
#include <hip/hip_runtime.h>
#include <hip/hip_bf16.h>
#include <stdint.h>

#define NN 50000
#define NE 600000
#define NP 200000
#define SCAN_CHUNK 1024
#define NB_SCAN ((NN + SCAN_CHUNK - 1) / SCAN_CHUNK)   // 49

// bucketed CSR build
#define NBUK 49            // node buckets of 1024 (50000 >> 10 -> 0..48)
#define BCAP 16384         // staging capacity per bucket (mean 12.2K, >30 sigma slack)
#define EPB  2048          // edges per pass-1 block
#define PB_BKT ((NE + EPB - 1) / EPB)        // 293

// prep_all block ranges
#define PB_W    400                          // weight prep: 102400 threads
#define PB_CNT  ((NE + 255) / 256)           // 2344
#define PB_PF   ((NP * 32 / 8 + 255) / 256)  // 3125

// csr_embed block ranges
#define CB_CSR NBUK                          // 49
#define CB_EMB ((NN + 127) / 128)            // 391

typedef __attribute__((ext_vector_type(8))) short short8;
typedef __attribute__((ext_vector_type(4))) float f32x4;

static __device__ __forceinline__ unsigned short f2bf(float f) {
  union { float f; unsigned u; } a; a.f = f;
  unsigned r = a.u + 0x7fff + ((a.u >> 16) & 1);
  return (unsigned short)(r >> 16);
}
static __device__ __forceinline__ float bf2f(unsigned short h) {
  union { unsigned u; float f; } a; a.u = ((unsigned)h) << 16;
  return a.f;
}
static __device__ __forceinline__ float lo16f(unsigned w) {
  union { unsigned u; float f; } a; a.u = w << 16; return a.f;
}
static __device__ __forceinline__ float hi16f(unsigned w) {
  union { unsigned u; float f; } a; a.u = w & 0xffff0000u; return a.f;
}

// ---------------- fused prep: weights + degree count + pf cast + edge bucketing ----------------

__global__ __launch_bounds__(256) void prep_all(
    const float* __restrict__ embW, const float* __restrict__ convW,
    const float* __restrict__ W1, const float* __restrict__ W2,
    const int* __restrict__ erow, const int* __restrict__ ecol,
    const float* __restrict__ pf,
    unsigned short* __restrict__ embT, unsigned short* __restrict__ convT,
    unsigned short* __restrict__ W1T, unsigned short* __restrict__ W2T,
    int* __restrict__ counts, unsigned short* __restrict__ pf_bf,
    int* __restrict__ bcur, unsigned* __restrict__ staging) {
  const int b = blockIdx.x, t = threadIdx.x;
  if (b < PB_W) {
    int idx = b * 256 + t;
    if (idx < 8192) {
      int n = idx >> 6, k = idx & 63;
      embT[idx] = f2bf(embW[(size_t)k * 128 + n]);
    } else if (idx < 8192 + 49152) {
      int i2 = idx - 8192;
      int l = i2 >> 14, n = (i2 >> 7) & 127, k = i2 & 127;
      convT[i2] = f2bf(convW[(size_t)l * 16384 + (size_t)k * 128 + n]);
    } else if (idx < 8192 + 49152 + 36864) {
      int i3 = idx - 57344;
      int n = i3 / 288, k = i3 % 288;
      W1T[i3] = f2bf(W1[(size_t)k * 128 + n]);
    } else if (idx < 8192 + 49152 + 36864 + 8192) {
      int i4 = idx - 94208;
      int n = i4 >> 7, k = i4 & 127;
      W2T[i4] = f2bf(W2[(size_t)k * 64 + n]);
    }
  } else if (b < PB_W + PB_CNT) {
    int e = (b - PB_W) * 256 + t;
    if (e < NE) atomicAdd(&counts[erow[e]], 1);
  } else if (b < PB_W + PB_CNT + PB_PF) {
    int i = (b - PB_W - PB_CNT) * 256 + t;   // group of 8 elements
    if (i < NP * 32 / 8) {
      const float4* s = (const float4*)(pf + (size_t)i * 8);
      float4 v0 = s[0], v1 = s[1];
      short8 o;
      o[0] = (short)f2bf(v0.x); o[1] = (short)f2bf(v0.y);
      o[2] = (short)f2bf(v0.z); o[3] = (short)f2bf(v0.w);
      o[4] = (short)f2bf(v1.x); o[5] = (short)f2bf(v1.y);
      o[6] = (short)f2bf(v1.z); o[7] = (short)f2bf(v1.w);
      *(short8*)(pf_bf + (size_t)i * 8) = o;
    }
  } else {
    // ---- bucket pass 1: partition edges into 49 node-range buckets, coalesced ----
    __shared__ int hist[NBUK];
    __shared__ int base[NBUK];
    const int bb = b - (PB_W + PB_CNT + PB_PF);
    const int e0 = bb * EPB;
    for (int i = t; i < NBUK; i += 256) hist[i] = 0;
    __syncthreads();
    int rr[8], cc8[8], off8[8];
#pragma unroll
    for (int q = 0; q < 8; ++q) {
      int e = e0 + q * 256 + t;
      rr[q] = -1;
      if (e < NE) {
        rr[q] = erow[e];
        cc8[q] = ecol[e];
        off8[q] = atomicAdd(&hist[rr[q] >> 10], 1);
      }
    }
    __syncthreads();
    for (int i = t; i < NBUK; i += 256) base[i] = atomicAdd(&bcur[i], hist[i]);
    __syncthreads();
#pragma unroll
    for (int q = 0; q < 8; ++q) {
      if (rr[q] >= 0) {
        int bk = rr[q] >> 10;
        staging[(size_t)bk * BCAP + base[bk] + off8[q]] =
            ((unsigned)rr[q] << 16) | (unsigned)cc8[q];
      }
    }
  }
}

// ---------------- graph scan ----------------

__global__ __launch_bounds__(256) void scan_partial_dis(const int* __restrict__ counts,
                                                        int* __restrict__ bsum,
                                                        float* __restrict__ dis) {
  const int b = blockIdx.x, t = threadIdx.x;
  const int base = b * SCAN_CHUNK;
  int s = 0;
  for (int j = t; j < SCAN_CHUNK; j += 256) {
    int i = base + j;
    if (i < NN) {
      int cv = counts[i];
      s += cv;
      dis[i] = rsqrtf((float)cv + 1.0f);
    }
  }
  __shared__ int red[4];
#pragma unroll
  for (int off = 32; off; off >>= 1) s += __shfl_down(s, off);
  if ((t & 63) == 0) red[t >> 6] = s;
  __syncthreads();
  if (t == 0) bsum[b] = red[0] + red[1] + red[2] + red[3];
}

__global__ __launch_bounds__(256) void scan_final(const int* __restrict__ counts,
                                                  const int* __restrict__ bsum,
                                                  int* __restrict__ row_ptr) {
  const int b = blockIdx.x, t = threadIdx.x;
  __shared__ int sb[64];
  if (t < 64) {                       // wave 0: exclusive prefix of bsum[49]
    int v = (t < NB_SCAN) ? bsum[t] : 0;
    int orig = v;
#pragma unroll
    for (int off = 1; off < 64; off <<= 1) {
      int u = __shfl_up(v, off);
      if (t >= off) v += u;
    }
    sb[t] = v - orig;
  }
  const int i0 = b * SCAN_CHUNK + t * 4;
  int c[4]; int s = 0;
#pragma unroll
  for (int r = 0; r < 4; ++r) { int i = i0 + r; c[r] = (i < NN) ? counts[i] : 0; s += c[r]; }
  __shared__ int sc[256];
  sc[t] = s;
  __syncthreads();
  for (int off = 1; off < 256; off <<= 1) {
    int add = (t >= off) ? sc[t - off] : 0;
    __syncthreads();
    sc[t] += add;
    __syncthreads();
  }
  int run = sb[b] + sc[t] - s;
#pragma unroll
  for (int r = 0; r < 4; ++r) {
    int i = i0 + r;
    if (i < NN) { row_ptr[i] = run; run += c[r]; }
  }
  if (b == 0 && t == 0) row_ptr[NN] = NE;
}

// ---------------- fused: bucket pass 2 (CSR segment build, coalesced) + embed GEMM ----------------

__global__ __launch_bounds__(256) void csr_embed(
    const int* __restrict__ bcur, const unsigned* __restrict__ staging,
    const int* __restrict__ row_ptr, int* __restrict__ csr_col,
    const float* __restrict__ atom, const unsigned short* __restrict__ embT,
    const float* __restrict__ embB, const float* __restrict__ dis,
    unsigned short* __restrict__ outb) {
  if (blockIdx.x < CB_CSR) {
    __shared__ unsigned short lcsr[BCAP];   // 32 KB: csr segment image (u16 cols)
    __shared__ int lcur[1024];              // 4 KB: per-node local cursors
    const int bk = blockIdx.x, t = threadIdx.x;
    const int lo = bk << 10;
    const int hi = (lo + 1024 < NN) ? lo + 1024 : NN;
    const int segbase = row_ptr[lo];
    for (int n = lo + t; n < hi; n += 256) lcur[n - lo] = row_ptr[n] - segbase;
    __syncthreads();
    const int cnt = bcur[bk];
    const unsigned* st = staging + (size_t)bk * BCAP;
    for (int j = t; j < cnt; j += 256) {
      unsigned rc = st[j];
      int pos = atomicAdd(&lcur[(rc >> 16) - lo], 1);
      lcsr[pos] = (unsigned short)(rc & 0xFFFFu);
    }
    __syncthreads();
    const int seglen = row_ptr[hi] - segbase;
    for (int j = t; j < seglen; j += 256)
      csr_col[segbase + j] = (int)lcsr[j];
    return;
  }
  // ---- embed: A fp32 split in-register (2 MFMAs), B single bf16 plane ----
  const int bid  = blockIdx.x - CB_CSR;
  const int K    = 64;
  const int tid  = threadIdx.x;
  const int lane = tid & 63;
  const int w    = tid >> 6;
  const int l15  = lane & 15;
  const int khi  = (lane >> 4) * 8;
  const int rowb = bid * 128 + w * 32;

  int ar[2];
#pragma unroll
  for (int rt = 0; rt < 2; ++rt) {
    int r = rowb + rt * 16 + l15;
    ar[rt] = (r < NN) ? r : NN - 1;
  }

  f32x4 acc[2][8];
#pragma unroll
  for (int rt = 0; rt < 2; ++rt)
#pragma unroll
    for (int ct = 0; ct < 8; ++ct) acc[rt][ct] = (f32x4){0.f, 0.f, 0.f, 0.f};

#pragma unroll
  for (int kb = 0; kb < K; kb += 32) {
    short8 ahi[2], alo[2];
#pragma unroll
    for (int rt = 0; rt < 2; ++rt) {
      const float* asrc = atom + (size_t)ar[rt] * K + kb + khi;
      float4 va0 = *(const float4*)(asrc);
      float4 va1 = *(const float4*)(asrc + 4);
      float av[8] = {va0.x, va0.y, va0.z, va0.w, va1.x, va1.y, va1.z, va1.w};
#pragma unroll
      for (int j = 0; j < 8; ++j) {
        unsigned short h = f2bf(av[j]);
        ahi[rt][j] = (short)h;
        alo[rt][j] = (short)f2bf(av[j] - bf2f(h));
      }
    }
#pragma unroll
    for (int ct = 0; ct < 8; ++ct) {
      short8 bfrag = *(const short8*)(embT + (size_t)(ct * 16 + l15) * K + kb + khi);
#pragma unroll
      for (int rt = 0; rt < 2; ++rt) {
        acc[rt][ct] = __builtin_amdgcn_mfma_f32_16x16x32_bf16(ahi[rt], bfrag, acc[rt][ct], 0, 0, 0);
        acc[rt][ct] = __builtin_amdgcn_mfma_f32_16x16x32_bf16(alo[rt], bfrag, acc[rt][ct], 0, 0, 0);
      }
    }
  }

#pragma unroll
  for (int rt = 0; rt < 2; ++rt) {
    const int orow0 = rowb + rt * 16 + (lane >> 4) * 4;
    float dv[4];
#pragma unroll
    for (int r = 0; r < 4; ++r) dv[r] = (orow0 + r < NN) ? dis[orow0 + r] : 0.f;
#pragma unroll
    for (int ct = 0; ct < 8; ++ct) {
      int col = ct * 16 + l15;
      float bb = embB[col];
#pragma unroll
      for (int r = 0; r < 4; ++r) {
        int orow = orow0 + r;
        if (orow < NN) {
          float v = (acc[rt][ct][r] + bb) * dv[r];
          outb[(size_t)orow * 128 + col] = f2bf(v);
        }
      }
    }
  }
}

// ---------------- aggregation v4 (round-10/11/12 proven) ----------------

__global__ __launch_bounds__(256) void agg4_kernel(const unsigned short* __restrict__ xsb,
    const int* __restrict__ row_ptr, const int* __restrict__ csr_col,
    const float* __restrict__ dis, unsigned short* __restrict__ y_bf) {
  const int t = threadIdx.x;
  const int n = blockIdx.x * 4 + (t >> 6);
  if (n >= NN) return;
  const int l    = t & 63;
  const int half = l >> 5;
  const int cl   = l & 31;
  const uint2* xs2 = (const uint2*)xsb;

  float a0, a1, a2, a3;
  {
    uint2 v = make_uint2(0u, 0u);
    if (half == 0) v = xs2[(size_t)n * 32 + cl];
    a0 = lo16f(v.x); a1 = hi16f(v.x);
    a2 = lo16f(v.y); a3 = hi16f(v.y);
  }

  const int s = row_ptr[n], e = row_ptr[n + 1];
  for (int j0 = s; j0 < e; j0 += 16) {
    int idx[8];
#pragma unroll
    for (int q = 0; q < 8; ++q) {
      int j = j0 + 2 * q + half;
      idx[q] = (j < e) ? csr_col[j] : -1;
    }
    uint2 ww[8];
#pragma unroll
    for (int q = 0; q < 8; ++q) {
      int r = (idx[q] < 0) ? 0 : idx[q];
      ww[q] = xs2[(size_t)r * 32 + cl];
    }
#pragma unroll
    for (int q = 0; q < 8; ++q) {
      if (idx[q] < 0) { ww[q].x = 0u; ww[q].y = 0u; }
      a0 += lo16f(ww[q].x); a1 += hi16f(ww[q].x);
      a2 += lo16f(ww[q].y); a3 += hi16f(ww[q].y);
    }
  }

  a0 += __shfl_xor(a0, 32);
  a1 += __shfl_xor(a1, 32);
  a2 += __shfl_xor(a2, 32);
  a3 += __shfl_xor(a3, 32);

  if (half == 0) {
    float dv = dis[n];
    uint2 o;
    o.x = (unsigned)f2bf(dv * a0) | ((unsigned)f2bf(dv * a1) << 16);
    o.y = (unsigned)f2bf(dv * a2) | ((unsigned)f2bf(dv * a3) << 16);
    ((uint2*)y_bf)[(size_t)n * 32 + cl] = o;
  }
}

// ---------------- conv GEMM: single bf16 plane A and B, 1 MFMA/ktile ----------------

template<int MODE>
__global__ __launch_bounds__(256) void conv_gemm(
    const unsigned short* __restrict__ Ab,
    const unsigned short* __restrict__ BT,
    const float* __restrict__ bias, const float* __restrict__ dis,
    const float* __restrict__ g, const float* __restrict__ be,
    const float* __restrict__ mn, const float* __restrict__ vr,
    unsigned short* __restrict__ outb) {
  const int K    = 128;
  const int tid  = threadIdx.x;
  const int lane = tid & 63;
  const int w    = tid >> 6;
  const int l15  = lane & 15;
  const int khi  = (lane >> 4) * 8;
  const int rowb = blockIdx.x * 128 + w * 32;

  int ar[2];
#pragma unroll
  for (int rt = 0; rt < 2; ++rt) {
    int r = rowb + rt * 16 + l15;
    ar[rt] = (r < NN) ? r : NN - 1;
  }

  f32x4 acc[2][8];
#pragma unroll
  for (int rt = 0; rt < 2; ++rt)
#pragma unroll
    for (int ct = 0; ct < 8; ++ct) acc[rt][ct] = (f32x4){0.f, 0.f, 0.f, 0.f};

#pragma unroll
  for (int kb = 0; kb < K; kb += 32) {
    short8 afr[2];
#pragma unroll
    for (int rt = 0; rt < 2; ++rt)
      afr[rt] = *(const short8*)(Ab + (size_t)ar[rt] * K + kb + khi);
#pragma unroll
    for (int ct = 0; ct < 8; ++ct) {
      short8 bfrag = *(const short8*)(BT + (size_t)(ct * 16 + l15) * K + kb + khi);
#pragma unroll
      for (int rt = 0; rt < 2; ++rt)
        acc[rt][ct] = __builtin_amdgcn_mfma_f32_16x16x32_bf16(afr[rt], bfrag, acc[rt][ct], 0, 0, 0);
    }
  }

#pragma unroll
  for (int rt = 0; rt < 2; ++rt) {
    const int orow0 = rowb + rt * 16 + (lane >> 4) * 4;
    float dv[4];
    if constexpr (MODE == 1) {
#pragma unroll
      for (int r = 0; r < 4; ++r) dv[r] = (orow0 + r < NN) ? dis[orow0 + r] : 0.f;
    }
#pragma unroll
    for (int ct = 0; ct < 8; ++ct) {
      int col = ct * 16 + l15;
      float bb = bias[col];
      float inv = rsqrtf(vr[col] + 1e-5f);
      float scale = g[col] * inv;
      float shift = be[col] - mn[col] * scale;
#pragma unroll
      for (int r = 0; r < 4; ++r) {
        int orow = orow0 + r;
        if (orow < NN) {
          float v = fmaxf((acc[rt][ct][r] + bb) * scale + shift, 0.f);
          if constexpr (MODE == 1) v *= dv[r];
          outb[(size_t)orow * 128 + col] = f2bf(v);
        }
      }
    }
  }
}

// ---------------- MFMA pair MLP: 1-wave blocks, 32 pairs, barrier-free ----------------
// Same dataflow/order as the proven 4-wave version (bit-identical results); waves were
// already independent, so blocks are now 64 threads for maximal scheduler packing.

__global__ __launch_bounds__(64, 8) void mlp2_kernel(
    const unsigned short* __restrict__ xb, const int* __restrict__ pairs,
    const unsigned short* __restrict__ pfb,
    const unsigned short* __restrict__ W1T, const float* __restrict__ b1,
    const unsigned short* __restrict__ W2T, const float* __restrict__ b2,
    const float* __restrict__ W3, const float* __restrict__ b3,
    float* __restrict__ out) {
  __shared__ unsigned short H1[32 * 136];

  const int lane = threadIdx.x & 63;
  const int pb   = blockIdx.x * 32;
  const int l15  = lane & 15;
  const int khi  = (lane >> 4) * 8;
  const int rq   = (lane >> 4) * 4;

  int gp0 = pb + l15;       if (gp0 >= NP) gp0 = NP - 1;
  int gp1 = pb + 16 + l15;  if (gp1 >= NP) gp1 = NP - 1;
  const int2 pr0 = ((const int2*)pairs)[gp0];
  const int2 pr1 = ((const int2*)pairs)[gp1];

  short8 af[18];
#pragma unroll
  for (int kb = 0; kb < 4; ++kb) {
    af[kb]     = *(const short8*)(xb + (size_t)pr0.x * 128 + kb * 32 + khi);
    af[4 + kb] = *(const short8*)(xb + (size_t)pr0.y * 128 + kb * 32 + khi);
    af[9 + kb]     = *(const short8*)(xb + (size_t)pr1.x * 128 + kb * 32 + khi);
    af[9 + 4 + kb] = *(const short8*)(xb + (size_t)pr1.y * 128 + kb * 32 + khi);
  }
  af[8]  = *(const short8*)(pfb + (size_t)gp0 * 32 + khi);
  af[17] = *(const short8*)(pfb + (size_t)gp1 * 32 + khi);

  f32x4 acc[2][8];
#pragma unroll
  for (int p = 0; p < 2; ++p)
#pragma unroll
    for (int c = 0; c < 8; ++c) acc[p][c] = (f32x4){0.f, 0.f, 0.f, 0.f};

#pragma unroll
  for (int kb = 0; kb < 9; ++kb) {
    const unsigned short* wrow = W1T + (size_t)kb * 32 + khi;
#pragma unroll
    for (int ct = 0; ct < 8; ++ct) {
      short8 bfrag = *(const short8*)(wrow + (size_t)(ct * 16 + l15) * 288);
      acc[0][ct] = __builtin_amdgcn_mfma_f32_16x16x32_bf16(af[kb], bfrag, acc[0][ct], 0, 0, 0);
      acc[1][ct] = __builtin_amdgcn_mfma_f32_16x16x32_bf16(af[9 + kb], bfrag, acc[1][ct], 0, 0, 0);
    }
  }

#pragma unroll
  for (int ct = 0; ct < 8; ++ct) {
    float bv = b1[ct * 16 + l15];
    int col = ct * 16 + l15;
#pragma unroll
    for (int p = 0; p < 2; ++p) {
#pragma unroll
      for (int r = 0; r < 4; ++r) {
        int row = p * 16 + rq + r;
        float v = fmaxf(acc[p][ct][r] + bv, 0.f);
        H1[row * 136 + col] = f2bf(v);
      }
    }
  }
  // no barrier: single wave, LDS deps enforced by lgkmcnt

  f32x4 acc2[2][4];
#pragma unroll
  for (int p = 0; p < 2; ++p)
#pragma unroll
    for (int c = 0; c < 4; ++c) acc2[p][c] = (f32x4){0.f, 0.f, 0.f, 0.f};

#pragma unroll
  for (int kb = 0; kb < 4; ++kb) {
    int ko = kb * 32 + khi;
    short8 a0 = *(const short8*)&H1[(l15) * 136 + ko];
    short8 a1 = *(const short8*)&H1[(16 + l15) * 136 + ko];
    const unsigned short* wrow = W2T + (size_t)ko;
#pragma unroll
    for (int ct = 0; ct < 4; ++ct) {
      short8 bfrag = *(const short8*)(wrow + (size_t)(ct * 16 + l15) * 128);
      acc2[0][ct] = __builtin_amdgcn_mfma_f32_16x16x32_bf16(a0, bfrag, acc2[0][ct], 0, 0, 0);
      acc2[1][ct] = __builtin_amdgcn_mfma_f32_16x16x32_bf16(a1, bfrag, acc2[1][ct], 0, 0, 0);
    }
  }

  float w3v[4], b2v[4];
#pragma unroll
  for (int ct = 0; ct < 4; ++ct) {
    w3v[ct] = W3[ct * 16 + l15];
    b2v[ct] = b2[ct * 16 + l15];
  }
  float b3v = b3[0];
#pragma unroll
  for (int p = 0; p < 2; ++p) {
#pragma unroll
    for (int r = 0; r < 4; ++r) {
      float s = 0.f;
#pragma unroll
      for (int ct = 0; ct < 4; ++ct) {
        float h2 = fmaxf(acc2[p][ct][r] + b2v[ct], 0.f);
        s += h2 * w3v[ct];
      }
      s += __shfl_xor(s, 1);
      s += __shfl_xor(s, 2);
      s += __shfl_xor(s, 4);
      s += __shfl_xor(s, 8);
      int row = pb + p * 16 + rq + r;
      if (l15 == 0 && row < NP) out[row] = s + b3v;
    }
  }
}

// ---------------- launch ----------------

extern "C" void kernel_launch(void* const* d_in, const int* in_sizes, int n_in,
                              void* d_out, int out_size, void* d_ws, size_t ws_size,
                              hipStream_t stream) {
  (void)in_sizes; (void)n_in; (void)out_size; (void)ws_size;
  const float* atom  = (const float*)d_in[0];
  const int*   eidx  = (const int*)d_in[1];
  const int*   pairs = (const int*)d_in[2];
  const float* pfeat = (const float*)d_in[3];
  const float* embW  = (const float*)d_in[4];
  const float* embB  = (const float*)d_in[5];
  const float* convW = (const float*)d_in[6];
  const float* convB = (const float*)d_in[7];
  const float* bng   = (const float*)d_in[8];
  const float* bnb   = (const float*)d_in[9];
  const float* bnm   = (const float*)d_in[10];
  const float* bnv   = (const float*)d_in[11];
  const float* W1    = (const float*)d_in[12];
  const float* b1    = (const float*)d_in[13];
  const float* W2    = (const float*)d_in[14];
  const float* b2    = (const float*)d_in[15];
  const float* W3    = (const float*)d_in[16];
  const float* b3    = (const float*)d_in[17];
  float* out = (float*)d_out;

  uintptr_t base = (uintptr_t)d_ws;
  auto alloc = [&](size_t bytes) -> uintptr_t {
    uintptr_t p = base;
    base += (bytes + 255) & ~(size_t)255;
    return p;
  };
  int*      counts  = (int*)alloc((size_t)NN * 4);
  int*      row_ptr = (int*)alloc((size_t)(NN + 1) * 4);
  int*      csr_col = (int*)alloc((size_t)NE * 4);
  float*    dis     = (float*)alloc((size_t)NN * 4);
  int*      bsum    = (int*)alloc(64 * 4);
  int*      bcur    = (int*)alloc(64 * 4);
  unsigned* staging = (unsigned*)alloc((size_t)NBUK * BCAP * 4);
  unsigned short* xs_bf = (unsigned short*)alloc((size_t)NN * 128 * 2);
  unsigned short* y_bf  = (unsigned short*)alloc((size_t)NN * 128 * 2);
  unsigned short* pf_bf = (unsigned short*)alloc((size_t)NP * 32 * 2);
  unsigned short* embT  = (unsigned short*)alloc(8192 * 2);
  unsigned short* convT = (unsigned short*)alloc(49152 * 2);
  unsigned short* W1T   = (unsigned short*)alloc(36864 * 2);
  unsigned short* W2T   = (unsigned short*)alloc(8192 * 2);

  const int* erow = eidx;
  const int* ecol = eidx + NE;

  hipMemsetAsync(counts, 0, (size_t)NN * 4, stream);
  hipMemsetAsync(bcur, 0, 64 * 4, stream);
  prep_all<<<PB_W + PB_CNT + PB_PF + PB_BKT, 256, 0, stream>>>(
      embW, convW, W1, W2, erow, ecol, pfeat,
      embT, convT, W1T, W2T, counts, pf_bf, bcur, staging);
  scan_partial_dis<<<NB_SCAN, 256, 0, stream>>>(counts, bsum, dis);
  scan_final<<<NB_SCAN, 256, 0, stream>>>(counts, bsum, row_ptr);

  // fused: coalesced CSR segment build + embed GEMM
  csr_embed<<<CB_CSR + CB_EMB, 256, 0, stream>>>(
      bcur, staging, row_ptr, csr_col, atom, embT, embB, dis, xs_bf);

  for (int l = 0; l < 3; ++l) {
    agg4_kernel<<<(NN + 3) / 4, 256, 0, stream>>>(xs_bf, row_ptr, csr_col, dis, y_bf);
    if (l < 2) {
      conv_gemm<1><<<(NN + 127) / 128, 256, 0, stream>>>(
          y_bf, convT + (size_t)l * 16384, convB + (size_t)l * 128, dis,
          bng + (size_t)l * 128, bnb + (size_t)l * 128,
          bnm + (size_t)l * 128, bnv + (size_t)l * 128, xs_bf);
    } else {
      conv_gemm<2><<<(NN + 127) / 128, 256, 0, stream>>>(
          y_bf, convT + (size_t)l * 16384, convB + (size_t)l * 128, nullptr,
          bng + (size_t)l * 128, bnb + (size_t)l * 128,
          bnm + (size_t)l * 128, bnv + (size_t)l * 128, xs_bf);
    }
  }

  mlp2_kernel<<<NP / 32, 64, 0, stream>>>(xs_bf, pairs, pf_bf,
                                          W1T, b1, W2T, b2, W3, b3, out);
}